// Round 1
// baseline (1877.637 us; speedup 1.0000x reference)
//
#include <hip/hip_runtime.h>
#include <math.h>

// FuzzyDirGCN — fp32 implementation.
// Restructure: matmul-before-scatter so only ONE atomic accumulator per layer:
//   h = segsum(y1[src]*wf + y2[src]*wb -> dst) + x@Wself + (bs2d+bd2s+bself)
// where y1 = x@Ws2d, y2 = x@Wd2s.

constexpr int D = 128;

__global__ __launch_bounds__(256) void edge_wdeg_kernel(
    const float* __restrict__ theta, const int* __restrict__ src, const int* __restrict__ dst,
    float* __restrict__ wf, float* __restrict__ wb,
    float* __restrict__ degfo, float* __restrict__ degfi,
    float* __restrict__ degbo, float* __restrict__ degbi, int E)
{
    int e = blockIdx.x * 256 + threadIdx.x;
    if (e >= E) return;
    float s, c;
    sincosf(theta[e], &s, &c);
    float f = c * c, b = s * s;
    wf[e] = f; wb[e] = b;
    int u = src[e], v = dst[e];
    atomicAdd(&degfo[u], f);
    atomicAdd(&degfi[v], f);
    atomicAdd(&degbo[u], b);
    atomicAdd(&degbi[v], b);
}

__global__ __launch_bounds__(256) void edge_norm_kernel(
    const int* __restrict__ src, const int* __restrict__ dst,
    const float* __restrict__ degfo, const float* __restrict__ degfi,
    const float* __restrict__ degbo, const float* __restrict__ degbi,
    float* __restrict__ wf, float* __restrict__ wb, int E)
{
    int e = blockIdx.x * 256 + threadIdx.x;
    if (e >= E) return;
    int u = src[e], v = dst[e];
    wf[e] = wf[e] * rsqrtf(degfo[u] * degfi[v] + 1e-12f);
    wb[e] = wb[e] * rsqrtf(degbo[u] * degbi[v] + 1e-12f);
}

// y1 = x@W1, y2 = x@W2, y3 = x@W3 + (b1+b2+b3).  x:[N,128], W:[128,128].
// Block: 256 threads, 32 rows. Thread: 4 rows x 4 cols register tile.
__global__ __launch_bounds__(256) void matmul3_kernel(
    const float* __restrict__ x,
    const float* __restrict__ W1, const float* __restrict__ W2, const float* __restrict__ W3,
    const float* __restrict__ b1, const float* __restrict__ b2, const float* __restrict__ b3,
    float* __restrict__ y1, float* __restrict__ y2, float* __restrict__ y3, int N)
{
    __shared__ float xs[32 * 132];   // +4 pad breaks bank aliasing
    const int tid = threadIdx.x;
    const int row0 = blockIdx.x * 32;
    #pragma unroll
    for (int j = 0; j < 4; ++j) {
        int g4 = tid + j * 256;           // float4 slot within 32x128 tile
        int r = g4 >> 5, c4 = g4 & 31;
        float4 v = make_float4(0.f, 0.f, 0.f, 0.f);
        if (row0 + r < N)
            v = reinterpret_cast<const float4*>(x + (size_t)(row0 + r) * D)[c4];
        *reinterpret_cast<float4*>(xs + r * 132 + c4 * 4) = v;
    }
    __syncthreads();

    const int cg = tid & 31;   // col group: cols cg*4..+3
    const int rg = tid >> 5;   // row group: rows rg*4..+3
    const float* Wm[3] = {W1, W2, W3};
    float* Ym[3] = {y1, y2, y3};

    #pragma unroll
    for (int m = 0; m < 3; ++m) {
        const float* __restrict__ W = Wm[m];
        float a[4][4];
        #pragma unroll
        for (int i = 0; i < 4; ++i)
            #pragma unroll
            for (int j = 0; j < 4; ++j) a[i][j] = 0.f;

        for (int k = 0; k < 128; k += 4) {
            float4 w0 = *reinterpret_cast<const float4*>(W + (size_t)(k + 0) * 128 + cg * 4);
            float4 w1 = *reinterpret_cast<const float4*>(W + (size_t)(k + 1) * 128 + cg * 4);
            float4 w2 = *reinterpret_cast<const float4*>(W + (size_t)(k + 2) * 128 + cg * 4);
            float4 w3 = *reinterpret_cast<const float4*>(W + (size_t)(k + 3) * 128 + cg * 4);
            #pragma unroll
            for (int i = 0; i < 4; ++i) {
                float4 xv = *reinterpret_cast<const float4*>(xs + (rg * 4 + i) * 132 + k);
                a[i][0] += xv.x * w0.x + xv.y * w1.x + xv.z * w2.x + xv.w * w3.x;
                a[i][1] += xv.x * w0.y + xv.y * w1.y + xv.z * w2.y + xv.w * w3.y;
                a[i][2] += xv.x * w0.z + xv.y * w1.z + xv.z * w2.z + xv.w * w3.z;
                a[i][3] += xv.x * w0.w + xv.y * w1.w + xv.z * w2.w + xv.w * w3.w;
            }
        }

        float bias[4] = {0.f, 0.f, 0.f, 0.f};
        if (m == 2) {
            #pragma unroll
            for (int j = 0; j < 4; ++j)
                bias[j] = b1[cg * 4 + j] + b2[cg * 4 + j] + b3[cg * 4 + j];
        }
        #pragma unroll
        for (int i = 0; i < 4; ++i) {
            int r = row0 + rg * 4 + i;
            if (r < N) {
                float4 o = make_float4(a[i][0] + bias[0], a[i][1] + bias[1],
                                       a[i][2] + bias[2], a[i][3] + bias[3]);
                *reinterpret_cast<float4*>(Ym[m] + (size_t)r * 128 + cg * 4) = o;
            }
        }
    }
}

// acc[dst] += wf*y1[src] + wb*y2[src].  One wave per edge, 2 feats/lane.
__global__ __launch_bounds__(256) void edge_agg_kernel(
    const int* __restrict__ src, const int* __restrict__ dst,
    const float* __restrict__ wf, const float* __restrict__ wb,
    const float* __restrict__ y1, const float* __restrict__ y2,
    float* __restrict__ acc, int E)
{
    int e = blockIdx.x * 4 + (threadIdx.x >> 6);
    if (e >= E) return;
    int lane = threadIdx.x & 63;
    int u = src[e], v = dst[e];
    float f = wf[e], b = wb[e];
    float2 a1 = reinterpret_cast<const float2*>(y1 + (size_t)u * 128)[lane];
    float2 a2 = reinterpret_cast<const float2*>(y2 + (size_t)u * 128)[lane];
    float cx = f * a1.x + b * a2.x;
    float cy = f * a1.y + b * a2.y;
    float* p = acc + (size_t)v * 128 + lane * 2;
    atomicAdd(p, cx);
    atomicAdd(p + 1, cy);
}

__global__ __launch_bounds__(256) void relu_rownorm_kernel(float* __restrict__ h, int N)
{
    int row = blockIdx.x * 4 + (threadIdx.x >> 6);
    if (row >= N) return;
    int lane = threadIdx.x & 63;
    float2* p = reinterpret_cast<float2*>(h + (size_t)row * 128) + lane;
    float2 v = *p;
    v.x = fmaxf(v.x, 0.f);
    v.y = fmaxf(v.y, 0.f);
    float ss = v.x * v.x + v.y * v.y;
    #pragma unroll
    for (int m = 1; m < 64; m <<= 1) ss += __shfl_xor(ss, m);
    float scale = 1.f / fmaxf(sqrtf(ss), 1e-12f);
    v.x *= scale; v.y *= scale;
    *p = v;
}

// out = x@W + b.  x:[N,128], W:[128,64].  64 rows/block, 4x4 per thread.
__global__ __launch_bounds__(256) void readout_kernel(
    const float* __restrict__ x, const float* __restrict__ W,
    const float* __restrict__ bias, float* __restrict__ out, int N)
{
    __shared__ float xs[64 * 132];
    const int tid = threadIdx.x;
    const int row0 = blockIdx.x * 64;
    #pragma unroll
    for (int j = 0; j < 8; ++j) {
        int g4 = tid + j * 256;
        int r = g4 >> 5, c4 = g4 & 31;
        float4 v = make_float4(0.f, 0.f, 0.f, 0.f);
        if (row0 + r < N)
            v = reinterpret_cast<const float4*>(x + (size_t)(row0 + r) * D)[c4];
        *reinterpret_cast<float4*>(xs + r * 132 + c4 * 4) = v;
    }
    __syncthreads();

    const int cg = tid & 15;   // cols cg*4..+3 of 64
    const int rg = tid >> 4;   // rows rg*4..+3 of 64
    float a[4][4];
    #pragma unroll
    for (int i = 0; i < 4; ++i)
        #pragma unroll
        for (int j = 0; j < 4; ++j) a[i][j] = 0.f;

    for (int k = 0; k < 128; k += 4) {
        float4 w0 = *reinterpret_cast<const float4*>(W + (size_t)(k + 0) * 64 + cg * 4);
        float4 w1 = *reinterpret_cast<const float4*>(W + (size_t)(k + 1) * 64 + cg * 4);
        float4 w2 = *reinterpret_cast<const float4*>(W + (size_t)(k + 2) * 64 + cg * 4);
        float4 w3 = *reinterpret_cast<const float4*>(W + (size_t)(k + 3) * 64 + cg * 4);
        #pragma unroll
        for (int i = 0; i < 4; ++i) {
            float4 xv = *reinterpret_cast<const float4*>(xs + (rg * 4 + i) * 132 + k);
            a[i][0] += xv.x * w0.x + xv.y * w1.x + xv.z * w2.x + xv.w * w3.x;
            a[i][1] += xv.x * w0.y + xv.y * w1.y + xv.z * w2.y + xv.w * w3.y;
            a[i][2] += xv.x * w0.z + xv.y * w1.z + xv.z * w2.z + xv.w * w3.z;
            a[i][3] += xv.x * w0.w + xv.y * w1.w + xv.z * w2.w + xv.w * w3.w;
        }
    }
    #pragma unroll
    for (int i = 0; i < 4; ++i) {
        int r = row0 + rg * 4 + i;
        if (r < N) {
            float4 o = make_float4(a[i][0] + bias[cg * 4 + 0], a[i][1] + bias[cg * 4 + 1],
                                   a[i][2] + bias[cg * 4 + 2], a[i][3] + bias[cg * 4 + 3]);
            *reinterpret_cast<float4*>(out + (size_t)r * 64 + cg * 4) = o;
        }
    }
}

extern "C" void kernel_launch(void* const* d_in, const int* in_sizes, int n_in,
                              void* d_out, int out_size, void* d_ws, size_t ws_size,
                              hipStream_t stream)
{
    const float* x     = (const float*)d_in[0];
    const int*   ei    = (const int*)d_in[1];
    const float* theta = (const float*)d_in[2];
    const float* Ws2d  = (const float*)d_in[3];
    const float* Wd2s  = (const float*)d_in[4];
    const float* Wself = (const float*)d_in[5];
    const float* bs2d  = (const float*)d_in[6];
    const float* bd2s  = (const float*)d_in[7];
    const float* bself = (const float*)d_in[8];
    const float* W_ro  = (const float*)d_in[9];
    const float* b_ro  = (const float*)d_in[10];
    float* out = (float*)d_out;

    const int N = in_sizes[0] / D;          // 50000
    const int E = in_sizes[2];              // 800000
    const int L = in_sizes[3] / (D * D);    // 2

    const int* src = ei;
    const int* dst = ei + E;

    float* ws    = (float*)d_ws;
    float* degfo = ws;
    float* degfi = degfo + N;
    float* degbo = degfi + N;
    float* degbi = degbo + N;
    float* wfn   = degbi + N;
    float* wbn   = wfn + E;
    float* y1    = wbn + E;
    float* y2    = y1 + (size_t)N * D;
    float* accA  = y2 + (size_t)N * D;
    float* accB  = accA + (size_t)N * D;

    hipMemsetAsync(degfo, 0, (size_t)4 * N * sizeof(float), stream);
    edge_wdeg_kernel<<<(E + 255) / 256, 256, 0, stream>>>(
        theta, src, dst, wfn, wbn, degfo, degfi, degbo, degbi, E);
    edge_norm_kernel<<<(E + 255) / 256, 256, 0, stream>>>(
        src, dst, degfo, degfi, degbo, degbi, wfn, wbn, E);

    const float* xin = x;
    float* accs[2] = {accA, accB};
    for (int i = 0; i < L; ++i) {
        float* acc = accs[i & 1];
        matmul3_kernel<<<(N + 31) / 32, 256, 0, stream>>>(
            xin,
            Ws2d + (size_t)i * D * D, Wd2s + (size_t)i * D * D, Wself + (size_t)i * D * D,
            bs2d + (size_t)i * D, bd2s + (size_t)i * D, bself + (size_t)i * D,
            y1, y2, acc, N);
        edge_agg_kernel<<<(E + 3) / 4, 256, 0, stream>>>(
            src, dst, wfn, wbn, y1, y2, acc, E);
        if (i != L - 1)
            relu_rownorm_kernel<<<(N + 3) / 4, 256, 0, stream>>>(acc, N);
        xin = acc;
    }
    readout_kernel<<<(N + 63) / 64, 256, 0, stream>>>(xin, W_ro, b_ro, out, N);
}

// Round 3
// 864.069 us; speedup vs baseline: 2.1730x; 2.1730x over previous
//
#include <hip/hip_runtime.h>
#include <math.h>

// FuzzyDirGCN — fp32, CSR-sorted aggregation (no float atomics in hot path).
// Restructure: matmul-before-scatter:
//   h = csr_sum_over_in_edges(wf*y1[src] + wb*y2[src]) + x@Wself + (bs2d+bd2s+bself)
// where y1 = x@Ws2d, y2 = x@Wd2s.  CSR (by dst) built once, reused both layers.

constexpr int D = 128;

// Pass 1: edge weights' degree accumulation + dst histogram (into cnt).
__global__ __launch_bounds__(256) void edge_wdeg_kernel(
    const float* __restrict__ theta, const int* __restrict__ src, const int* __restrict__ dst,
    float* __restrict__ degfo, float* __restrict__ degfi,
    float* __restrict__ degbo, float* __restrict__ degbi,
    int* __restrict__ cnt, int E)
{
    int e = blockIdx.x * 256 + threadIdx.x;
    if (e >= E) return;
    float s, c;
    sincosf(theta[e], &s, &c);
    float f = c * c, b = s * s;
    int u = src[e], v = dst[e];
    atomicAdd(&degfo[u], f);
    atomicAdd(&degfi[v], f);
    atomicAdd(&degbo[u], b);
    atomicAdd(&degbi[v], b);
    atomicAdd(&cnt[v], 1);
}

// Exclusive prefix sum of cnt[0..N) -> startv[0..N).  Single block, 1024 thr.
__global__ __launch_bounds__(1024) void scan_kernel(
    const int* __restrict__ cnt, int* __restrict__ startv, int N)
{
    __shared__ int wsum[16];
    __shared__ int carry;
    if (threadIdx.x == 0) carry = 0;
    __syncthreads();
    const int lane = threadIdx.x & 63, wid = threadIdx.x >> 6;
    for (int base = 0; base < N; base += 1024) {
        int i = base + threadIdx.x;
        int v = (i < N) ? cnt[i] : 0;
        int x = v;                      // inclusive wave scan
        #pragma unroll
        for (int d = 1; d < 64; d <<= 1) {
            int t = __shfl_up(x, d);
            if (lane >= d) x += t;
        }
        if (lane == 63) wsum[wid] = x;
        __syncthreads();
        if (wid == 0) {
            int s = (lane < 16) ? wsum[lane] : 0;
            #pragma unroll
            for (int d = 1; d < 16; d <<= 1) {
                int t = __shfl_up(s, d);
                if (lane >= d) s += t;
            }
            if (lane < 16) wsum[lane] = s;
        }
        __syncthreads();
        int woff = (wid == 0) ? 0 : wsum[wid - 1];
        if (i < N) startv[i] = carry + woff + x - v;   // exclusive
        __syncthreads();                               // all read carry first
        if (threadIdx.x == 1023) carry += wsum[15];
        __syncthreads();
    }
}

// Scatter edges into dst-sorted order; fold in symmetric normalization.
// Uses startv[v] as atomic ticket; afterwards startv[v] == end of bin v.
__global__ __launch_bounds__(256) void scatter_kernel(
    const float* __restrict__ theta, const int* __restrict__ src, const int* __restrict__ dst,
    const float* __restrict__ degfo, const float* __restrict__ degfi,
    const float* __restrict__ degbo, const float* __restrict__ degbi,
    int* __restrict__ startv, int* __restrict__ s_src,
    float* __restrict__ s_wf, float* __restrict__ s_wb, int E)
{
    int e = blockIdx.x * 256 + threadIdx.x;
    if (e >= E) return;
    int u = src[e], v = dst[e];
    float s, c;
    sincosf(theta[e], &s, &c);
    float f = c * c, b = s * s;
    f *= rsqrtf(degfo[u] * degfi[v] + 1e-12f);
    b *= rsqrtf(degbo[u] * degbi[v] + 1e-12f);
    int pos = atomicAdd(&startv[v], 1);
    s_src[pos] = u;
    s_wf[pos] = f;
    s_wb[pos] = b;
}

// y1 = x@W1, y2 = x@W2, y3 = x@W3 + (b1+b2+b3).  x:[N,128], W:[128,128].
__global__ __launch_bounds__(256) void matmul3_kernel(
    const float* __restrict__ x,
    const float* __restrict__ W1, const float* __restrict__ W2, const float* __restrict__ W3,
    const float* __restrict__ b1, const float* __restrict__ b2, const float* __restrict__ b3,
    float* __restrict__ y1, float* __restrict__ y2, float* __restrict__ y3, int N)
{
    __shared__ float xs[32 * 132];
    const int tid = threadIdx.x;
    const int row0 = blockIdx.x * 32;
    #pragma unroll
    for (int j = 0; j < 4; ++j) {
        int g4 = tid + j * 256;
        int r = g4 >> 5, c4 = g4 & 31;
        float4 v = make_float4(0.f, 0.f, 0.f, 0.f);
        if (row0 + r < N)
            v = reinterpret_cast<const float4*>(x + (size_t)(row0 + r) * D)[c4];
        *reinterpret_cast<float4*>(xs + r * 132 + c4 * 4) = v;
    }
    __syncthreads();

    const int cg = tid & 31;
    const int rg = tid >> 5;
    const float* Wm[3] = {W1, W2, W3};
    float* Ym[3] = {y1, y2, y3};

    #pragma unroll
    for (int m = 0; m < 3; ++m) {
        const float* __restrict__ W = Wm[m];
        float a[4][4];
        #pragma unroll
        for (int i = 0; i < 4; ++i)
            #pragma unroll
            for (int j = 0; j < 4; ++j) a[i][j] = 0.f;

        for (int k = 0; k < 128; k += 4) {
            float4 w0 = *reinterpret_cast<const float4*>(W + (size_t)(k + 0) * 128 + cg * 4);
            float4 w1 = *reinterpret_cast<const float4*>(W + (size_t)(k + 1) * 128 + cg * 4);
            float4 w2 = *reinterpret_cast<const float4*>(W + (size_t)(k + 2) * 128 + cg * 4);
            float4 w3 = *reinterpret_cast<const float4*>(W + (size_t)(k + 3) * 128 + cg * 4);
            #pragma unroll
            for (int i = 0; i < 4; ++i) {
                float4 xv = *reinterpret_cast<const float4*>(xs + (rg * 4 + i) * 132 + k);
                a[i][0] += xv.x * w0.x + xv.y * w1.x + xv.z * w2.x + xv.w * w3.x;
                a[i][1] += xv.x * w0.y + xv.y * w1.y + xv.z * w2.y + xv.w * w3.y;
                a[i][2] += xv.x * w0.z + xv.y * w1.z + xv.z * w2.z + xv.w * w3.z;
                a[i][3] += xv.x * w0.w + xv.y * w1.w + xv.z * w2.w + xv.w * w3.w;
            }
        }

        float bias[4] = {0.f, 0.f, 0.f, 0.f};
        if (m == 2) {
            #pragma unroll
            for (int j = 0; j < 4; ++j)
                bias[j] = b1[cg * 4 + j] + b2[cg * 4 + j] + b3[cg * 4 + j];
        }
        #pragma unroll
        for (int i = 0; i < 4; ++i) {
            int r = row0 + rg * 4 + i;
            if (r < N) {
                float4 o = make_float4(a[i][0] + bias[0], a[i][1] + bias[1],
                                       a[i][2] + bias[2], a[i][3] + bias[3]);
                *reinterpret_cast<float4*>(Ym[m] + (size_t)r * 128 + cg * 4) = o;
            }
        }
    }
}

// One wave per dst node: acc[v] += sum_e wf*y1[src] + wb*y2[src]; optional
// fused ReLU + row L2 norm.  endv[v] = end of bin v (bin v starts at endv[v-1]).
template <bool NORM>
__global__ __launch_bounds__(256) void agg_csr_kernel(
    const int* __restrict__ endv, const int* __restrict__ s_src,
    const float* __restrict__ s_wf, const float* __restrict__ s_wb,
    const float* __restrict__ y1, const float* __restrict__ y2,
    float* __restrict__ acc, int N)
{
    int v = blockIdx.x * 4 + (threadIdx.x >> 6);
    if (v >= N) return;
    int lane = threadIdx.x & 63;
    int beg = (v == 0) ? 0 : endv[v - 1];
    int end = endv[v];
    float2* prow = reinterpret_cast<float2*>(acc + (size_t)v * 128) + lane;
    float2 sum = *prow;   // y3 = x@Wself + biases, written by matmul3
    for (int e = beg; e < end; ++e) {
        int u = s_src[e];
        float f = s_wf[e], b = s_wb[e];
        float2 a1 = reinterpret_cast<const float2*>(y1 + (size_t)u * 128)[lane];
        float2 a2 = reinterpret_cast<const float2*>(y2 + (size_t)u * 128)[lane];
        sum.x = fmaf(f, a1.x, fmaf(b, a2.x, sum.x));
        sum.y = fmaf(f, a1.y, fmaf(b, a2.y, sum.y));
    }
    if (NORM) {
        sum.x = fmaxf(sum.x, 0.f);
        sum.y = fmaxf(sum.y, 0.f);
        float ss = sum.x * sum.x + sum.y * sum.y;
        #pragma unroll
        for (int m = 1; m < 64; m <<= 1) ss += __shfl_xor(ss, m);
        float sc = 1.f / fmaxf(sqrtf(ss), 1e-12f);
        sum.x *= sc;
        sum.y *= sc;
    }
    *prow = sum;
}

// out = x@W + b.  x:[N,128], W:[128,64].
__global__ __launch_bounds__(256) void readout_kernel(
    const float* __restrict__ x, const float* __restrict__ W,
    const float* __restrict__ bias, float* __restrict__ out, int N)
{
    __shared__ float xs[64 * 132];
    const int tid = threadIdx.x;
    const int row0 = blockIdx.x * 64;
    #pragma unroll
    for (int j = 0; j < 8; ++j) {
        int g4 = tid + j * 256;
        int r = g4 >> 5, c4 = g4 & 31;
        float4 v = make_float4(0.f, 0.f, 0.f, 0.f);
        if (row0 + r < N)
            v = reinterpret_cast<const float4*>(x + (size_t)(row0 + r) * D)[c4];
        *reinterpret_cast<float4*>(xs + r * 132 + c4 * 4) = v;
    }
    __syncthreads();

    const int cg = tid & 15;
    const int rg = tid >> 4;
    float a[4][4];
    #pragma unroll
    for (int i = 0; i < 4; ++i)
        #pragma unroll
        for (int j = 0; j < 4; ++j) a[i][j] = 0.f;

    for (int k = 0; k < 128; k += 4) {
        float4 w0 = *reinterpret_cast<const float4*>(W + (size_t)(k + 0) * 64 + cg * 4);
        float4 w1 = *reinterpret_cast<const float4*>(W + (size_t)(k + 1) * 64 + cg * 4);
        float4 w2 = *reinterpret_cast<const float4*>(W + (size_t)(k + 2) * 64 + cg * 4);
        float4 w3 = *reinterpret_cast<const float4*>(W + (size_t)(k + 3) * 64 + cg * 4);
        #pragma unroll
        for (int i = 0; i < 4; ++i) {
            float4 xv = *reinterpret_cast<const float4*>(xs + (rg * 4 + i) * 132 + k);
            a[i][0] += xv.x * w0.x + xv.y * w1.x + xv.z * w2.x + xv.w * w3.x;
            a[i][1] += xv.x * w0.y + xv.y * w1.y + xv.z * w2.y + xv.w * w3.y;
            a[i][2] += xv.x * w0.z + xv.y * w1.z + xv.z * w2.z + xv.w * w3.z;
            a[i][3] += xv.x * w0.w + xv.y * w1.w + xv.z * w2.w + xv.w * w3.w;
        }
    }
    #pragma unroll
    for (int i = 0; i < 4; ++i) {
        int r = row0 + rg * 4 + i;
        if (r < N) {
            float4 o = make_float4(a[i][0] + bias[cg * 4 + 0], a[i][1] + bias[cg * 4 + 1],
                                   a[i][2] + bias[cg * 4 + 2], a[i][3] + bias[cg * 4 + 3]);
            *reinterpret_cast<float4*>(out + (size_t)r * 64 + cg * 4) = o;
        }
    }
}

extern "C" void kernel_launch(void* const* d_in, const int* in_sizes, int n_in,
                              void* d_out, int out_size, void* d_ws, size_t ws_size,
                              hipStream_t stream)
{
    const float* x     = (const float*)d_in[0];
    const int*   ei    = (const int*)d_in[1];
    const float* theta = (const float*)d_in[2];
    const float* Ws2d  = (const float*)d_in[3];
    const float* Wd2s  = (const float*)d_in[4];
    const float* Wself = (const float*)d_in[5];
    const float* bs2d  = (const float*)d_in[6];
    const float* bd2s  = (const float*)d_in[7];
    const float* bself = (const float*)d_in[8];
    const float* W_ro  = (const float*)d_in[9];
    const float* b_ro  = (const float*)d_in[10];
    float* out = (float*)d_out;

    const int N = in_sizes[0] / D;          // 50000
    const int E = in_sizes[2];              // 800000
    const int L = in_sizes[3] / (D * D);    // 2

    const int* src = ei;
    const int* dst = ei + E;

    // Workspace layout (4B elems): 6N + 3E + 4*N*D floats (~113 MB @ N=50k,E=800k)
    float* wsf   = (float*)d_ws;
    float* degfo = wsf;                       // N
    float* degfi = degfo + N;                 // N
    float* degbo = degfi + N;                 // N
    float* degbi = degbo + N;                 // N
    int*   cnt   = (int*)(degbi + N);         // N   (zeroed with degs: 5N)
    int*   startv= cnt + N;                   // N   (scan output; end[] post-scatter)
    int*   s_src = startv + N;                // E
    float* s_wf  = (float*)(s_src + E);       // E
    float* s_wb  = s_wf + E;                  // E
    float* y1    = s_wb + E;                  // N*D
    float* y2    = y1 + (size_t)N * D;        // N*D
    float* accA  = y2 + (size_t)N * D;        // N*D
    float* accB  = accA + (size_t)N * D;      // N*D

    hipMemsetAsync(degfo, 0, (size_t)5 * N * sizeof(float), stream);
    edge_wdeg_kernel<<<(E + 255) / 256, 256, 0, stream>>>(
        theta, src, dst, degfo, degfi, degbo, degbi, cnt, E);
    scan_kernel<<<1, 1024, 0, stream>>>(cnt, startv, N);
    scatter_kernel<<<(E + 255) / 256, 256, 0, stream>>>(
        theta, src, dst, degfo, degfi, degbo, degbi, startv, s_src, s_wf, s_wb, E);

    const float* xin = x;
    float* accs[2] = {accA, accB};
    for (int i = 0; i < L; ++i) {
        float* acc = accs[i & 1];
        matmul3_kernel<<<(N + 31) / 32, 256, 0, stream>>>(
            xin,
            Ws2d + (size_t)i * D * D, Wd2s + (size_t)i * D * D, Wself + (size_t)i * D * D,
            bs2d + (size_t)i * D, bd2s + (size_t)i * D, bself + (size_t)i * D,
            y1, y2, acc, N);
        if (i != L - 1)
            agg_csr_kernel<true><<<(N + 3) / 4, 256, 0, stream>>>(
                startv, s_src, s_wf, s_wb, y1, y2, acc, N);
        else
            agg_csr_kernel<false><<<(N + 3) / 4, 256, 0, stream>>>(
                startv, s_src, s_wf, s_wb, y1, y2, acc, N);
        xin = acc;
    }
    readout_kernel<<<(N + 63) / 64, 256, 0, stream>>>(xin, W_ro, b_ro, out, N);
}

// Round 5
// 785.468 us; speedup vs baseline: 2.3905x; 1.1001x over previous
//
#include <hip/hip_runtime.h>
#include <math.h>

// FuzzyDirGCN — fp32, CSR aggregation, packed-atomic degree pass.
//   h = csr_sum_over_in_edges(wf*y1[src] + wb*y2[src]) + x@Wself + biases
// Degrees: one u64 atomic per edge endpoint, packing (count<<44)|fix24(cos^2).
// degb = count - degf  (sin^2 = 1 - cos^2).

constexpr int D = 128;
typedef unsigned long long u64;

__device__ __forceinline__ u64 pack_wc(float f) {
    return (1ULL << 44) | (u64)(f * 16777216.0f + 0.5f);   // 2^24 fixed point
}
__device__ __forceinline__ void unpack_wc(u64 p, float& sumf, float& cnt) {
    cnt  = (float)(unsigned)(p >> 44);
    sumf = (float)(p & ((1ULL << 44) - 1)) * (1.0f / 16777216.0f);
}

// Pass 1: packed degree accumulation (src side and dst side).
__global__ __launch_bounds__(256) void edge_wdeg_kernel(
    const float* __restrict__ theta, const int* __restrict__ src, const int* __restrict__ dst,
    u64* __restrict__ packed_out, u64* __restrict__ packed_in, int E)
{
    int e = blockIdx.x * 256 + threadIdx.x;
    if (e >= E) return;
    float c = cosf(theta[e]);
    u64 p = pack_wc(c * c);
    atomicAdd(&packed_out[src[e]], p);
    atomicAdd(&packed_in[dst[e]], p);
}

// Exclusive prefix sum of in-counts (high bits of packed_in) -> startv.
__global__ __launch_bounds__(1024) void scan_kernel(
    const u64* __restrict__ packed_in, int* __restrict__ startv, int N)
{
    __shared__ int wsum[16];
    __shared__ int carry;
    if (threadIdx.x == 0) carry = 0;
    __syncthreads();
    const int lane = threadIdx.x & 63, wid = threadIdx.x >> 6;
    for (int base = 0; base < N; base += 1024) {
        int i = base + threadIdx.x;
        int v = (i < N) ? (int)(packed_in[i] >> 44) : 0;
        int x = v;
        #pragma unroll
        for (int d = 1; d < 64; d <<= 1) {
            int t = __shfl_up(x, d);
            if (lane >= d) x += t;
        }
        if (lane == 63) wsum[wid] = x;
        __syncthreads();
        if (wid == 0) {
            int s = (lane < 16) ? wsum[lane] : 0;
            #pragma unroll
            for (int d = 1; d < 16; d <<= 1) {
                int t = __shfl_up(s, d);
                if (lane >= d) s += t;
            }
            if (lane < 16) wsum[lane] = s;
        }
        __syncthreads();
        int woff = (wid == 0) ? 0 : wsum[wid - 1];
        if (i < N) startv[i] = carry + woff + x - v;   // exclusive
        __syncthreads();
        if (threadIdx.x == 1023) carry += wsum[15];
        __syncthreads();
    }
}

// Scatter edges into dst-sorted order with folded normalization.
// s_edge[pos] = {src, wf_bits, wb_bits, 0}.  startv becomes bin-end array.
__global__ __launch_bounds__(256) void scatter_kernel(
    const float* __restrict__ theta, const int* __restrict__ src, const int* __restrict__ dst,
    const u64* __restrict__ packed_out, const u64* __restrict__ packed_in,
    int* __restrict__ startv, int4* __restrict__ s_edge, int E)
{
    int e = blockIdx.x * 256 + threadIdx.x;
    if (e >= E) return;
    int u = src[e], v = dst[e];
    float s, c;
    sincosf(theta[e], &s, &c);
    float f = c * c, b = s * s;
    float fo, co, fi, ci;
    unpack_wc(packed_out[u], fo, co);
    unpack_wc(packed_in[v], fi, ci);
    float bo = co - fo, bi = ci - fi;            // sin^2 degrees
    f *= rsqrtf(fo * fi + 1e-12f);
    b *= rsqrtf(bo * bi + 1e-12f);
    int pos = atomicAdd(&startv[v], 1);
    s_edge[pos] = make_int4(u, __float_as_int(f), __float_as_int(b), 0);
}

// y1 = x@W1, y2 = x@W2, y3 = x@W3 + (b1+b2+b3).  x:[N,128], W:[128,128].
__global__ __launch_bounds__(256) void matmul3_kernel(
    const float* __restrict__ x,
    const float* __restrict__ W1, const float* __restrict__ W2, const float* __restrict__ W3,
    const float* __restrict__ b1, const float* __restrict__ b2, const float* __restrict__ b3,
    float* __restrict__ y1, float* __restrict__ y2, float* __restrict__ y3, int N)
{
    __shared__ float xs[32 * 132];
    const int tid = threadIdx.x;
    const int row0 = blockIdx.x * 32;
    #pragma unroll
    for (int j = 0; j < 4; ++j) {
        int g4 = tid + j * 256;
        int r = g4 >> 5, c4 = g4 & 31;
        float4 v = make_float4(0.f, 0.f, 0.f, 0.f);
        if (row0 + r < N)
            v = reinterpret_cast<const float4*>(x + (size_t)(row0 + r) * D)[c4];
        *reinterpret_cast<float4*>(xs + r * 132 + c4 * 4) = v;
    }
    __syncthreads();

    const int cg = tid & 31;
    const int rg = tid >> 5;
    const float* Wm[3] = {W1, W2, W3};
    float* Ym[3] = {y1, y2, y3};

    #pragma unroll
    for (int m = 0; m < 3; ++m) {
        const float* __restrict__ W = Wm[m];
        float a[4][4];
        #pragma unroll
        for (int i = 0; i < 4; ++i)
            #pragma unroll
            for (int j = 0; j < 4; ++j) a[i][j] = 0.f;

        for (int k = 0; k < 128; k += 4) {
            float4 w0 = *reinterpret_cast<const float4*>(W + (size_t)(k + 0) * 128 + cg * 4);
            float4 w1 = *reinterpret_cast<const float4*>(W + (size_t)(k + 1) * 128 + cg * 4);
            float4 w2 = *reinterpret_cast<const float4*>(W + (size_t)(k + 2) * 128 + cg * 4);
            float4 w3 = *reinterpret_cast<const float4*>(W + (size_t)(k + 3) * 128 + cg * 4);
            #pragma unroll
            for (int i = 0; i < 4; ++i) {
                float4 xv = *reinterpret_cast<const float4*>(xs + (rg * 4 + i) * 132 + k);
                a[i][0] += xv.x * w0.x + xv.y * w1.x + xv.z * w2.x + xv.w * w3.x;
                a[i][1] += xv.x * w0.y + xv.y * w1.y + xv.z * w2.y + xv.w * w3.y;
                a[i][2] += xv.x * w0.z + xv.y * w1.z + xv.z * w2.z + xv.w * w3.z;
                a[i][3] += xv.x * w0.w + xv.y * w1.w + xv.z * w2.w + xv.w * w3.w;
            }
        }

        float bias[4] = {0.f, 0.f, 0.f, 0.f};
        if (m == 2) {
            #pragma unroll
            for (int j = 0; j < 4; ++j)
                bias[j] = b1[cg * 4 + j] + b2[cg * 4 + j] + b3[cg * 4 + j];
        }
        #pragma unroll
        for (int i = 0; i < 4; ++i) {
            int r = row0 + rg * 4 + i;
            if (r < N) {
                float4 o = make_float4(a[i][0] + bias[0], a[i][1] + bias[1],
                                       a[i][2] + bias[2], a[i][3] + bias[3]);
                *reinterpret_cast<float4*>(Ym[m] + (size_t)r * 128 + cg * 4) = o;
            }
        }
    }
}

// One wave per dst node: acc[v] += sum_e wf*y1[src] + wb*y2[src].
template <bool NORM>
__global__ __launch_bounds__(256) void agg_csr_kernel(
    const int* __restrict__ endv, const int4* __restrict__ s_edge,
    const float* __restrict__ y1, const float* __restrict__ y2,
    float* __restrict__ acc, int N)
{
    int v = blockIdx.x * 4 + (threadIdx.x >> 6);
    if (v >= N) return;
    int lane = threadIdx.x & 63;
    int beg = (v == 0) ? 0 : endv[v - 1];
    int end = endv[v];
    float2* prow = reinterpret_cast<float2*>(acc + (size_t)v * 128) + lane;
    float2 sum = *prow;   // y3 = x@Wself + biases (from matmul3)
    int e = beg;
    for (; e + 1 < end; e += 2) {
        int4 E0 = s_edge[e], E1 = s_edge[e + 1];
        float f0 = __int_as_float(E0.y), b0 = __int_as_float(E0.z);
        float f1 = __int_as_float(E1.y), b1 = __int_as_float(E1.z);
        float2 a10 = reinterpret_cast<const float2*>(y1 + (size_t)E0.x * 128)[lane];
        float2 a20 = reinterpret_cast<const float2*>(y2 + (size_t)E0.x * 128)[lane];
        float2 a11 = reinterpret_cast<const float2*>(y1 + (size_t)E1.x * 128)[lane];
        float2 a21 = reinterpret_cast<const float2*>(y2 + (size_t)E1.x * 128)[lane];
        sum.x = fmaf(f0, a10.x, fmaf(b0, a20.x, sum.x));
        sum.y = fmaf(f0, a10.y, fmaf(b0, a20.y, sum.y));
        sum.x = fmaf(f1, a11.x, fmaf(b1, a21.x, sum.x));
        sum.y = fmaf(f1, a11.y, fmaf(b1, a21.y, sum.y));
    }
    if (e < end) {
        int4 E0 = s_edge[e];
        float f0 = __int_as_float(E0.y), b0 = __int_as_float(E0.z);
        float2 a10 = reinterpret_cast<const float2*>(y1 + (size_t)E0.x * 128)[lane];
        float2 a20 = reinterpret_cast<const float2*>(y2 + (size_t)E0.x * 128)[lane];
        sum.x = fmaf(f0, a10.x, fmaf(b0, a20.x, sum.x));
        sum.y = fmaf(f0, a10.y, fmaf(b0, a20.y, sum.y));
    }
    if (NORM) {
        sum.x = fmaxf(sum.x, 0.f);
        sum.y = fmaxf(sum.y, 0.f);
        float ss = sum.x * sum.x + sum.y * sum.y;
        #pragma unroll
        for (int m = 1; m < 64; m <<= 1) ss += __shfl_xor(ss, m);
        float sc = 1.f / fmaxf(sqrtf(ss), 1e-12f);
        sum.x *= sc;
        sum.y *= sc;
    }
    *prow = sum;
}

// out = x@W + b.  x:[N,128], W:[128,64].
__global__ __launch_bounds__(256) void readout_kernel(
    const float* __restrict__ x, const float* __restrict__ W,
    const float* __restrict__ bias, float* __restrict__ out, int N)
{
    __shared__ float xs[64 * 132];
    const int tid = threadIdx.x;
    const int row0 = blockIdx.x * 64;
    #pragma unroll
    for (int j = 0; j < 8; ++j) {
        int g4 = tid + j * 256;
        int r = g4 >> 5, c4 = g4 & 31;
        float4 v = make_float4(0.f, 0.f, 0.f, 0.f);
        if (row0 + r < N)
            v = reinterpret_cast<const float4*>(x + (size_t)(row0 + r) * D)[c4];
        *reinterpret_cast<float4*>(xs + r * 132 + c4 * 4) = v;
    }
    __syncthreads();

    const int cg = tid & 15;
    const int rg = tid >> 4;
    float a[4][4];
    #pragma unroll
    for (int i = 0; i < 4; ++i)
        #pragma unroll
        for (int j = 0; j < 4; ++j) a[i][j] = 0.f;

    for (int k = 0; k < 128; k += 4) {
        float4 w0 = *reinterpret_cast<const float4*>(W + (size_t)(k + 0) * 64 + cg * 4);
        float4 w1 = *reinterpret_cast<const float4*>(W + (size_t)(k + 1) * 64 + cg * 4);
        float4 w2 = *reinterpret_cast<const float4*>(W + (size_t)(k + 2) * 64 + cg * 4);
        float4 w3 = *reinterpret_cast<const float4*>(W + (size_t)(k + 3) * 64 + cg * 4);
        #pragma unroll
        for (int i = 0; i < 4; ++i) {
            float4 xv = *reinterpret_cast<const float4*>(xs + (rg * 4 + i) * 132 + k);
            a[i][0] += xv.x * w0.x + xv.y * w1.x + xv.z * w2.x + xv.w * w3.x;
            a[i][1] += xv.x * w0.y + xv.y * w1.y + xv.z * w2.y + xv.w * w3.y;
            a[i][2] += xv.x * w0.z + xv.y * w1.z + xv.z * w2.z + xv.w * w3.z;
            a[i][3] += xv.x * w0.w + xv.y * w1.w + xv.z * w2.w + xv.w * w3.w;
        }
    }
    #pragma unroll
    for (int i = 0; i < 4; ++i) {
        int r = row0 + rg * 4 + i;
        if (r < N) {
            float4 o = make_float4(a[i][0] + bias[cg * 4 + 0], a[i][1] + bias[cg * 4 + 1],
                                   a[i][2] + bias[cg * 4 + 2], a[i][3] + bias[cg * 4 + 3]);
            *reinterpret_cast<float4*>(out + (size_t)r * 64 + cg * 4) = o;
        }
    }
}

extern "C" void kernel_launch(void* const* d_in, const int* in_sizes, int n_in,
                              void* d_out, int out_size, void* d_ws, size_t ws_size,
                              hipStream_t stream)
{
    const float* x     = (const float*)d_in[0];
    const int*   ei    = (const int*)d_in[1];
    const float* theta = (const float*)d_in[2];
    const float* Ws2d  = (const float*)d_in[3];
    const float* Wd2s  = (const float*)d_in[4];
    const float* Wself = (const float*)d_in[5];
    const float* bs2d  = (const float*)d_in[6];
    const float* bd2s  = (const float*)d_in[7];
    const float* bself = (const float*)d_in[8];
    const float* W_ro  = (const float*)d_in[9];
    const float* b_ro  = (const float*)d_in[10];
    float* out = (float*)d_out;

    const int N = in_sizes[0] / D;          // 50000
    const int E = in_sizes[2];              // 800000
    const int L = in_sizes[3] / (D * D);    // 2

    const int* src = ei;
    const int* dst = ei + E;

    // Workspace layout: packed u64[2N] | startv int[N] | s_edge int4[E] | y1 y2 accA accB
    u64*  packed_out = (u64*)d_ws;                       // N u64
    u64*  packed_in  = packed_out + N;                   // N u64
    int*  startv     = (int*)(packed_in + N);            // N
    int4* s_edge     = (int4*)(startv + N);              // E int4
    float* y1   = (float*)(s_edge + E);                  // N*D
    float* y2   = y1 + (size_t)N * D;                    // N*D
    float* accA = y2 + (size_t)N * D;                    // N*D
    float* accB = accA + (size_t)N * D;                  // N*D

    hipMemsetAsync(packed_out, 0, (size_t)2 * N * sizeof(u64), stream);
    edge_wdeg_kernel<<<(E + 255) / 256, 256, 0, stream>>>(
        theta, src, dst, packed_out, packed_in, E);
    scan_kernel<<<1, 1024, 0, stream>>>(packed_in, startv, N);
    scatter_kernel<<<(E + 255) / 256, 256, 0, stream>>>(
        theta, src, dst, packed_out, packed_in, startv, s_edge, E);

    const float* xin = x;
    float* accs[2] = {accA, accB};
    for (int i = 0; i < L; ++i) {
        float* acc = accs[i & 1];
        matmul3_kernel<<<(N + 31) / 32, 256, 0, stream>>>(
            xin,
            Ws2d + (size_t)i * D * D, Wd2s + (size_t)i * D * D, Wself + (size_t)i * D * D,
            bs2d + (size_t)i * D, bd2s + (size_t)i * D, bself + (size_t)i * D,
            y1, y2, acc, N);
        if (i != L - 1)
            agg_csr_kernel<true><<<(N + 3) / 4, 256, 0, stream>>>(
                startv, s_edge, y1, y2, acc, N);
        else
            agg_csr_kernel<false><<<(N + 3) / 4, 256, 0, stream>>>(
                startv, s_edge, y1, y2, acc, N);
        xin = acc;
    }
    readout_kernel<<<(N + 63) / 64, 256, 0, stream>>>(xin, W_ro, b_ro, out, N);
}

// Round 7
// 630.098 us; speedup vs baseline: 2.9799x; 1.2466x over previous
//
#include <hip/hip_runtime.h>
#include <math.h>

// FuzzyDirGCN — CSR aggregation + MFMA (bf16 hi/lo split) matmuls.
//   h = csr_sum_over_in_edges(wf*y1[src] + wb*y2[src]) + x@Wself + biases
// y1 = x@Ws2d, y2 = x@Wd2s.  Matmuls via mfma_f32_16x16x32_bf16 with
// x = xhi + xlo, W = Whi + Wlo; D = xhi*Whi + xhi*Wlo + xlo*Whi (fp32 acc).

constexpr int D = 128;
typedef unsigned long long u64;
typedef __attribute__((ext_vector_type(8))) short bf16x8;
typedef __attribute__((ext_vector_type(4))) float f32x4;

__device__ __forceinline__ u64 pack_wc(float f) {
    return (1ULL << 44) | (u64)(f * 16777216.0f + 0.5f);   // 2^24 fixed point
}
__device__ __forceinline__ void unpack_wc(u64 p, float& sumf, float& cnt) {
    cnt  = (float)(unsigned)(p >> 44);
    sumf = (float)(p & ((1ULL << 44) - 1)) * (1.0f / 16777216.0f);
}

// split float -> (hi bf16 bits, lo bf16 bits), truncation both
__device__ __forceinline__ void split_bf16(float x, short& hi, short& lo) {
    unsigned xb = __float_as_uint(x);
    hi = (short)(xb >> 16);
    float h = __uint_as_float(xb & 0xffff0000u);
    lo = (short)(__float_as_uint(x - h) >> 16);
}

// ---------------- CSR build (unchanged from passing r5 kernel) ----------------
__global__ __launch_bounds__(256) void edge_wdeg_kernel(
    const float* __restrict__ theta, const int* __restrict__ src, const int* __restrict__ dst,
    u64* __restrict__ packed_out, u64* __restrict__ packed_in, int E)
{
    int e = blockIdx.x * 256 + threadIdx.x;
    if (e >= E) return;
    float c = cosf(theta[e]);
    u64 p = pack_wc(c * c);
    atomicAdd(&packed_out[src[e]], p);
    atomicAdd(&packed_in[dst[e]], p);
}

__global__ __launch_bounds__(1024) void scan_kernel(
    const u64* __restrict__ packed_in, int* __restrict__ startv, int N)
{
    __shared__ int wsum[16];
    __shared__ int carry;
    if (threadIdx.x == 0) carry = 0;
    __syncthreads();
    const int lane = threadIdx.x & 63, wid = threadIdx.x >> 6;
    for (int base = 0; base < N; base += 1024) {
        int i = base + threadIdx.x;
        int v = (i < N) ? (int)(packed_in[i] >> 44) : 0;
        int x = v;
        #pragma unroll
        for (int d = 1; d < 64; d <<= 1) {
            int t = __shfl_up(x, d);
            if (lane >= d) x += t;
        }
        if (lane == 63) wsum[wid] = x;
        __syncthreads();
        if (wid == 0) {
            int s = (lane < 16) ? wsum[lane] : 0;
            #pragma unroll
            for (int d = 1; d < 16; d <<= 1) {
                int t = __shfl_up(s, d);
                if (lane >= d) s += t;
            }
            if (lane < 16) wsum[lane] = s;
        }
        __syncthreads();
        int woff = (wid == 0) ? 0 : wsum[wid - 1];
        if (i < N) startv[i] = carry + woff + x - v;   // exclusive
        __syncthreads();
        if (threadIdx.x == 1023) carry += wsum[15];
        __syncthreads();
    }
}

__global__ __launch_bounds__(256) void scatter_kernel(
    const float* __restrict__ theta, const int* __restrict__ src, const int* __restrict__ dst,
    const u64* __restrict__ packed_out, const u64* __restrict__ packed_in,
    int* __restrict__ startv, int4* __restrict__ s_edge, int E)
{
    int e = blockIdx.x * 256 + threadIdx.x;
    if (e >= E) return;
    int u = src[e], v = dst[e];
    float s, c;
    sincosf(theta[e], &s, &c);
    float f = c * c, b = s * s;
    float fo, co, fi, ci;
    unpack_wc(packed_out[u], fo, co);
    unpack_wc(packed_in[v], fi, ci);
    float bo = co - fo, bi = ci - fi;            // sin^2 degrees
    f *= rsqrtf(fo * fi + 1e-12f);
    b *= rsqrtf(bo * bi + 1e-12f);
    int pos = atomicAdd(&startv[v], 1);
    s_edge[pos] = make_int4(u, __float_as_int(f), __float_as_int(b), 0);
}

// ---------------- W pre-pack into MFMA B-fragment layout ----------------
// wp layout (ushort): [m:3][c:8][t:4][lane:64][hi/lo:2][j:8]
// element (m,c,t,lane,h,j) = bf16 of W_m[t*32 + (lane>>4)*8 + j][c*16 + (lane&15)]
__global__ __launch_bounds__(256) void wpack_kernel(
    const float* __restrict__ W1, const float* __restrict__ W2, const float* __restrict__ W3,
    short* __restrict__ wp)
{
    int idx = blockIdx.x * 256 + threadIdx.x;     // ((m*8+c)*4+t)*64 + lane
    if (idx >= 3 * 8 * 4 * 64) return;
    int lane = idx & 63;
    int t = (idx >> 6) & 3;
    int c = (idx >> 8) & 7;
    int m = idx >> 11;
    const float* W = (m == 0) ? W1 : ((m == 1) ? W2 : W3);
    int col  = c * 16 + (lane & 15);
    int row0 = t * 32 + (lane >> 4) * 8;
    short hi[8], lo[8];
    #pragma unroll
    for (int j = 0; j < 8; ++j)
        split_bf16(W[(size_t)(row0 + j) * 128 + col], hi[j], lo[j]);
    short* dst = wp + (size_t)idx * 16;
    #pragma unroll
    for (int j = 0; j < 8; ++j) { dst[j] = hi[j]; dst[8 + j] = lo[j]; }
}

// ---------------- MFMA triple-matmul ----------------
// Block: 256 thr = 4 waves; block covers 32 rows; wave w: rows (w>>1)*16,
// cols (w&1)*64..+63 (4 col-frags of 16).  144 MFMA/wave.
__global__ __launch_bounds__(256, 4) void matmul3_mfma_kernel(
    const float* __restrict__ x, const short* __restrict__ wp,
    const float* __restrict__ b1, const float* __restrict__ b2, const float* __restrict__ b3,
    float* __restrict__ y1, float* __restrict__ y2, float* __restrict__ acc, int N)
{
    const int lane = threadIdx.x & 63, wid = threadIdx.x >> 6;
    const int row0 = blockIdx.x * 32 + (wid >> 1) * 16;
    const int chalf = (wid & 1) * 4;

    // Build A hi/lo fragments in registers from global x (row clamped; rows>=N unused).
    int arow = row0 + (lane & 15);
    if (arow >= N) arow = N - 1;
    const float* xrow = x + (size_t)arow * 128 + (lane >> 4) * 8;
    bf16x8 ahi[4], alo[4];
    #pragma unroll
    for (int t = 0; t < 4; ++t) {
        float4 v0 = *reinterpret_cast<const float4*>(xrow + t * 32);
        float4 v1 = *reinterpret_cast<const float4*>(xrow + t * 32 + 4);
        float f[8] = {v0.x, v0.y, v0.z, v0.w, v1.x, v1.y, v1.z, v1.w};
        #pragma unroll
        for (int j = 0; j < 8; ++j) {
            short h, l;
            split_bf16(f[j], h, l);
            ahi[t][j] = h;
            alo[t][j] = l;
        }
    }

    const int colbase = lane & 15;
    const int rbase = row0 + (lane >> 4) * 4;
    #pragma unroll
    for (int m = 0; m < 3; ++m) {
        float* Y = (m == 0) ? y1 : ((m == 1) ? y2 : acc);
        #pragma unroll
        for (int ci = 0; ci < 4; ++ci) {
            int c = chalf + ci;
            const short* bp = wp + (size_t)(m * 8 + c) * 4096 + lane * 16;
            f32x4 a = {0.f, 0.f, 0.f, 0.f};
            #pragma unroll
            for (int t = 0; t < 4; ++t) {
                bf16x8 bhi = *reinterpret_cast<const bf16x8*>(bp + t * 1024);
                bf16x8 blo = *reinterpret_cast<const bf16x8*>(bp + t * 1024 + 8);
                a = __builtin_amdgcn_mfma_f32_16x16x32_bf16(ahi[t], bhi, a, 0, 0, 0);
                a = __builtin_amdgcn_mfma_f32_16x16x32_bf16(ahi[t], blo, a, 0, 0, 0);
                a = __builtin_amdgcn_mfma_f32_16x16x32_bf16(alo[t], bhi, a, 0, 0, 0);
            }
            int col = c * 16 + colbase;
            if (m == 2) {
                float bias = b1[col] + b2[col] + b3[col];
                a[0] += bias; a[1] += bias; a[2] += bias; a[3] += bias;
            }
            #pragma unroll
            for (int r = 0; r < 4; ++r) {
                int rr = rbase + r;
                if (rr < N) Y[(size_t)rr * 128 + col] = a[r];
            }
        }
    }
}

// ---------------- CSR aggregation (unchanged) ----------------
template <bool NORM>
__global__ __launch_bounds__(256) void agg_csr_kernel(
    const int* __restrict__ endv, const int4* __restrict__ s_edge,
    const float* __restrict__ y1, const float* __restrict__ y2,
    float* __restrict__ acc, int N)
{
    int v = blockIdx.x * 4 + (threadIdx.x >> 6);
    if (v >= N) return;
    int lane = threadIdx.x & 63;
    int beg = (v == 0) ? 0 : endv[v - 1];
    int end = endv[v];
    float2* prow = reinterpret_cast<float2*>(acc + (size_t)v * 128) + lane;
    float2 sum = *prow;   // y3 = x@Wself + biases (from matmul3)
    int e = beg;
    for (; e + 1 < end; e += 2) {
        int4 E0 = s_edge[e], E1 = s_edge[e + 1];
        float f0 = __int_as_float(E0.y), b0 = __int_as_float(E0.z);
        float f1 = __int_as_float(E1.y), b1 = __int_as_float(E1.z);
        float2 a10 = reinterpret_cast<const float2*>(y1 + (size_t)E0.x * 128)[lane];
        float2 a20 = reinterpret_cast<const float2*>(y2 + (size_t)E0.x * 128)[lane];
        float2 a11 = reinterpret_cast<const float2*>(y1 + (size_t)E1.x * 128)[lane];
        float2 a21 = reinterpret_cast<const float2*>(y2 + (size_t)E1.x * 128)[lane];
        sum.x = fmaf(f0, a10.x, fmaf(b0, a20.x, sum.x));
        sum.y = fmaf(f0, a10.y, fmaf(b0, a20.y, sum.y));
        sum.x = fmaf(f1, a11.x, fmaf(b1, a21.x, sum.x));
        sum.y = fmaf(f1, a11.y, fmaf(b1, a21.y, sum.y));
    }
    if (e < end) {
        int4 E0 = s_edge[e];
        float f0 = __int_as_float(E0.y), b0 = __int_as_float(E0.z);
        float2 a10 = reinterpret_cast<const float2*>(y1 + (size_t)E0.x * 128)[lane];
        float2 a20 = reinterpret_cast<const float2*>(y2 + (size_t)E0.x * 128)[lane];
        sum.x = fmaf(f0, a10.x, fmaf(b0, a20.x, sum.x));
        sum.y = fmaf(f0, a10.y, fmaf(b0, a20.y, sum.y));
    }
    if (NORM) {
        sum.x = fmaxf(sum.x, 0.f);
        sum.y = fmaxf(sum.y, 0.f);
        float ss = sum.x * sum.x + sum.y * sum.y;
        #pragma unroll
        for (int m = 1; m < 64; m <<= 1) ss += __shfl_xor(ss, m);
        float sc = 1.f / fmaxf(sqrtf(ss), 1e-12f);
        sum.x *= sc;
        sum.y *= sc;
    }
    *prow = sum;
}

// ---------------- readout (fp32, unchanged) ----------------
__global__ __launch_bounds__(256) void readout_kernel(
    const float* __restrict__ x, const float* __restrict__ W,
    const float* __restrict__ bias, float* __restrict__ out, int N)
{
    __shared__ float xs[64 * 132];
    const int tid = threadIdx.x;
    const int row0 = blockIdx.x * 64;
    #pragma unroll
    for (int j = 0; j < 8; ++j) {
        int g4 = tid + j * 256;
        int r = g4 >> 5, c4 = g4 & 31;
        float4 v = make_float4(0.f, 0.f, 0.f, 0.f);
        if (row0 + r < N)
            v = reinterpret_cast<const float4*>(x + (size_t)(row0 + r) * D)[c4];
        *reinterpret_cast<float4*>(xs + r * 132 + c4 * 4) = v;
    }
    __syncthreads();

    const int cg = tid & 15;
    const int rg = tid >> 4;
    float a[4][4];
    #pragma unroll
    for (int i = 0; i < 4; ++i)
        #pragma unroll
        for (int j = 0; j < 4; ++j) a[i][j] = 0.f;

    for (int k = 0; k < 128; k += 4) {
        float4 w0 = *reinterpret_cast<const float4*>(W + (size_t)(k + 0) * 64 + cg * 4);
        float4 w1 = *reinterpret_cast<const float4*>(W + (size_t)(k + 1) * 64 + cg * 4);
        float4 w2 = *reinterpret_cast<const float4*>(W + (size_t)(k + 2) * 64 + cg * 4);
        float4 w3 = *reinterpret_cast<const float4*>(W + (size_t)(k + 3) * 64 + cg * 4);
        #pragma unroll
        for (int i = 0; i < 4; ++i) {
            float4 xv = *reinterpret_cast<const float4*>(xs + (rg * 4 + i) * 132 + k);
            a[i][0] += xv.x * w0.x + xv.y * w1.x + xv.z * w2.x + xv.w * w3.x;
            a[i][1] += xv.x * w0.y + xv.y * w1.y + xv.z * w2.y + xv.w * w3.y;
            a[i][2] += xv.x * w0.z + xv.y * w1.z + xv.z * w2.z + xv.w * w3.z;
            a[i][3] += xv.x * w0.w + xv.y * w1.w + xv.z * w2.w + xv.w * w3.w;
        }
    }
    #pragma unroll
    for (int i = 0; i < 4; ++i) {
        int r = row0 + rg * 4 + i;
        if (r < N) {
            float4 o = make_float4(a[i][0] + bias[cg * 4 + 0], a[i][1] + bias[cg * 4 + 1],
                                   a[i][2] + bias[cg * 4 + 2], a[i][3] + bias[cg * 4 + 3]);
            *reinterpret_cast<float4*>(out + (size_t)r * 64 + cg * 4) = o;
        }
    }
}

extern "C" void kernel_launch(void* const* d_in, const int* in_sizes, int n_in,
                              void* d_out, int out_size, void* d_ws, size_t ws_size,
                              hipStream_t stream)
{
    const float* x     = (const float*)d_in[0];
    const int*   ei    = (const int*)d_in[1];
    const float* theta = (const float*)d_in[2];
    const float* Ws2d  = (const float*)d_in[3];
    const float* Wd2s  = (const float*)d_in[4];
    const float* Wself = (const float*)d_in[5];
    const float* bs2d  = (const float*)d_in[6];
    const float* bd2s  = (const float*)d_in[7];
    const float* bself = (const float*)d_in[8];
    const float* W_ro  = (const float*)d_in[9];
    const float* b_ro  = (const float*)d_in[10];
    float* out = (float*)d_out;

    const int N = in_sizes[0] / D;          // 50000
    const int E = in_sizes[2];              // 800000
    const int L = in_sizes[3] / (D * D);    // 2

    const int* src = ei;
    const int* dst = ei + E;

    // Workspace: packed u64[2N] | startv int[N] | s_edge int4[E] | wpack short[L*98304]
    //            | y1 y2 accA accB float[N*D each]
    u64*  packed_out = (u64*)d_ws;                       // N u64
    u64*  packed_in  = packed_out + N;                   // N u64
    int*  startv     = (int*)(packed_in + N);            // N
    int4* s_edge     = (int4*)(startv + N);              // E int4
    short* wpack     = (short*)(s_edge + E);             // L * 98304 shorts
    float* y1   = (float*)(wpack + (size_t)L * 98304);   // N*D
    float* y2   = y1 + (size_t)N * D;                    // N*D
    float* accA = y2 + (size_t)N * D;                    // N*D
    float* accB = accA + (size_t)N * D;                  // N*D

    hipMemsetAsync(packed_out, 0, (size_t)2 * N * sizeof(u64), stream);
    edge_wdeg_kernel<<<(E + 255) / 256, 256, 0, stream>>>(
        theta, src, dst, packed_out, packed_in, E);
    scan_kernel<<<1, 1024, 0, stream>>>(packed_in, startv, N);
    scatter_kernel<<<(E + 255) / 256, 256, 0, stream>>>(
        theta, src, dst, packed_out, packed_in, startv, s_edge, E);
    for (int i = 0; i < L; ++i)
        wpack_kernel<<<(6144 + 255) / 256, 256, 0, stream>>>(
            Ws2d + (size_t)i * D * D, Wd2s + (size_t)i * D * D, Wself + (size_t)i * D * D,
            wpack + (size_t)i * 98304);

    const float* xin = x;
    float* accs[2] = {accA, accB};
    for (int i = 0; i < L; ++i) {
        float* acc = accs[i & 1];
        matmul3_mfma_kernel<<<(N + 31) / 32, 256, 0, stream>>>(
            xin, wpack + (size_t)i * 98304,
            bs2d + (size_t)i * D, bd2s + (size_t)i * D, bself + (size_t)i * D,
            y1, y2, acc, N);
        if (i != L - 1)
            agg_csr_kernel<true><<<(N + 3) / 4, 256, 0, stream>>>(
                startv, s_edge, y1, y2, acc, N);
        else
            agg_csr_kernel<false><<<(N + 3) / 4, 256, 0, stream>>>(
                startv, s_edge, y1, y2, acc, N);
        xin = acc;
    }
    readout_kernel<<<(N + 63) / 64, 256, 0, stream>>>(xin, W_ro, b_ro, out, N);
}

// Round 9
// 537.372 us; speedup vs baseline: 3.4941x; 1.1726x over previous
//
#include <hip/hip_runtime.h>
#include <math.h>

// FuzzyDirGCN — x-space CSR aggregation + fused 3-stream MFMA matmul.
//   a1[v] = sum_in wf*x[src], a2[v] = sum_in wb*x[src]   (one gather/edge)
//   h = a1@Ws2d + a2@Wd2s + x@Wself + (bs2d+bd2s+bself)  (one MFMA kernel)
// Matmul via mfma_f32_16x16x32_bf16 hi/lo split (fp32-grade accuracy).

constexpr int D = 128;
typedef unsigned long long u64;
typedef __attribute__((ext_vector_type(8))) short bf16x8;
typedef __attribute__((ext_vector_type(4))) float f32x4;

__device__ __forceinline__ u64 pack_wc(float f) {
    return (1ULL << 44) | (u64)(f * 16777216.0f + 0.5f);   // 2^24 fixed point
}
__device__ __forceinline__ void unpack_wc(u64 p, float& sumf, float& cnt) {
    cnt  = (float)(unsigned)(p >> 44);
    sumf = (float)(p & ((1ULL << 44) - 1)) * (1.0f / 16777216.0f);
}

__device__ __forceinline__ void split_bf16(float x, short& hi, short& lo) {
    unsigned xb = __float_as_uint(x);
    hi = (short)(xb >> 16);
    float h = __uint_as_float(xb & 0xffff0000u);
    lo = (short)(__float_as_uint(x - h) >> 16);
}

// ---------------- CSR build ----------------
__global__ __launch_bounds__(256) void edge_wdeg_kernel(
    const float* __restrict__ theta, const int* __restrict__ src, const int* __restrict__ dst,
    u64* __restrict__ packed_out, u64* __restrict__ packed_in, int E)
{
    int e = blockIdx.x * 256 + threadIdx.x;
    if (e >= E) return;
    float c = cosf(theta[e]);
    u64 p = pack_wc(c * c);
    atomicAdd(&packed_out[src[e]], p);
    atomicAdd(&packed_in[dst[e]], p);
}

__global__ __launch_bounds__(1024) void scan_kernel(
    const u64* __restrict__ packed_in, int* __restrict__ startv, int N)
{
    __shared__ int wsum[16];
    __shared__ int carry;
    if (threadIdx.x == 0) carry = 0;
    __syncthreads();
    const int lane = threadIdx.x & 63, wid = threadIdx.x >> 6;
    for (int base = 0; base < N; base += 1024) {
        int i = base + threadIdx.x;
        int v = (i < N) ? (int)(packed_in[i] >> 44) : 0;
        int x = v;
        #pragma unroll
        for (int d = 1; d < 64; d <<= 1) {
            int t = __shfl_up(x, d);
            if (lane >= d) x += t;
        }
        if (lane == 63) wsum[wid] = x;
        __syncthreads();
        if (wid == 0) {
            int s = (lane < 16) ? wsum[lane] : 0;
            #pragma unroll
            for (int d = 1; d < 16; d <<= 1) {
                int t = __shfl_up(s, d);
                if (lane >= d) s += t;
            }
            if (lane < 16) wsum[lane] = s;
        }
        __syncthreads();
        int woff = (wid == 0) ? 0 : wsum[wid - 1];
        if (i < N) startv[i] = carry + woff + x - v;   // exclusive
        __syncthreads();
        if (threadIdx.x == 1023) carry += wsum[15];
        __syncthreads();
    }
}

__global__ __launch_bounds__(256) void scatter_kernel(
    const float* __restrict__ theta, const int* __restrict__ src, const int* __restrict__ dst,
    const u64* __restrict__ packed_out, const u64* __restrict__ packed_in,
    int* __restrict__ startv, int4* __restrict__ s_edge, int E)
{
    int e = blockIdx.x * 256 + threadIdx.x;
    if (e >= E) return;
    int u = src[e], v = dst[e];
    float s, c;
    sincosf(theta[e], &s, &c);
    float f = c * c, b = s * s;
    float fo, co, fi, ci;
    unpack_wc(packed_out[u], fo, co);
    unpack_wc(packed_in[v], fi, ci);
    float bo = co - fo, bi = ci - fi;            // sin^2 degrees
    f *= rsqrtf(fo * fi + 1e-12f);
    b *= rsqrtf(bo * bi + 1e-12f);
    int pos = atomicAdd(&startv[v], 1);
    s_edge[pos] = make_int4(u, __float_as_int(f), __float_as_int(b), 0);
}

// ---------------- W pre-pack into MFMA B-fragment layout ----------------
// wp (ushort): [m:3][c:8][t:4][lane:64][hi/lo:2][j:8]
// element = bf16 of W_m[t*32 + (lane>>4)*8 + j][c*16 + (lane&15)]
__global__ __launch_bounds__(256) void wpack_kernel(
    const float* __restrict__ W1, const float* __restrict__ W2, const float* __restrict__ W3,
    short* __restrict__ wp)
{
    int idx = blockIdx.x * 256 + threadIdx.x;     // ((m*8+c)*4+t)*64 + lane
    if (idx >= 3 * 8 * 4 * 64) return;
    int lane = idx & 63;
    int t = (idx >> 6) & 3;
    int c = (idx >> 8) & 7;
    int m = idx >> 11;
    const float* W = (m == 0) ? W1 : ((m == 1) ? W2 : W3);
    int col  = c * 16 + (lane & 15);
    int row0 = t * 32 + (lane >> 4) * 8;
    short hi[8], lo[8];
    #pragma unroll
    for (int j = 0; j < 8; ++j)
        split_bf16(W[(size_t)(row0 + j) * 128 + col], hi[j], lo[j]);
    short* dst = wp + (size_t)idx * 16;
    #pragma unroll
    for (int j = 0; j < 8; ++j) { dst[j] = hi[j]; dst[8 + j] = lo[j]; }
}

// ---------------- x-space CSR aggregation ----------------
// One wave per dst node: a1[v] = sum wf*x[u], a2[v] = sum wb*x[u].
__global__ __launch_bounds__(256) void agg_x_kernel(
    const int* __restrict__ endv, const int4* __restrict__ s_edge,
    const float* __restrict__ x,
    float* __restrict__ a1, float* __restrict__ a2, int N)
{
    int v = blockIdx.x * 4 + (threadIdx.x >> 6);
    if (v >= N) return;
    int lane = threadIdx.x & 63;
    int beg = (v == 0) ? 0 : endv[v - 1];
    int end = endv[v];
    float2 s1 = make_float2(0.f, 0.f), s2 = make_float2(0.f, 0.f);
    int e = beg;
    for (; e + 1 < end; e += 2) {
        int4 E0 = s_edge[e], E1 = s_edge[e + 1];
        float f0 = __int_as_float(E0.y), b0 = __int_as_float(E0.z);
        float f1 = __int_as_float(E1.y), b1 = __int_as_float(E1.z);
        float2 x0 = reinterpret_cast<const float2*>(x + (size_t)E0.x * 128)[lane];
        float2 x1 = reinterpret_cast<const float2*>(x + (size_t)E1.x * 128)[lane];
        s1.x = fmaf(f0, x0.x, s1.x); s1.y = fmaf(f0, x0.y, s1.y);
        s2.x = fmaf(b0, x0.x, s2.x); s2.y = fmaf(b0, x0.y, s2.y);
        s1.x = fmaf(f1, x1.x, s1.x); s1.y = fmaf(f1, x1.y, s1.y);
        s2.x = fmaf(b1, x1.x, s2.x); s2.y = fmaf(b1, x1.y, s2.y);
    }
    if (e < end) {
        int4 E0 = s_edge[e];
        float f0 = __int_as_float(E0.y), b0 = __int_as_float(E0.z);
        float2 x0 = reinterpret_cast<const float2*>(x + (size_t)E0.x * 128)[lane];
        s1.x = fmaf(f0, x0.x, s1.x); s1.y = fmaf(f0, x0.y, s1.y);
        s2.x = fmaf(b0, x0.x, s2.x); s2.y = fmaf(b0, x0.y, s2.y);
    }
    reinterpret_cast<float2*>(a1 + (size_t)v * 128)[lane] = s1;
    reinterpret_cast<float2*>(a2 + (size_t)v * 128)[lane] = s2;
}

// ---------------- fused 3-stream MFMA matmul ----------------
// h = a1@W1 + a2@W2 + x@W3 + (b1+b2+b3).  Block: 4 waves, 64 rows; wave: 16
// rows x 128 cols.  144 MFMA/wave.
__global__ __launch_bounds__(256, 2) void matmul_fused_kernel(
    const float* __restrict__ a1, const float* __restrict__ a2,
    const float* __restrict__ xin, const short* __restrict__ wp,
    const float* __restrict__ b1, const float* __restrict__ b2, const float* __restrict__ b3,
    float* __restrict__ h, int N)
{
    const int lane = threadIdx.x & 63, wid = threadIdx.x >> 6;
    const int row0 = blockIdx.x * 64 + wid * 16;

    int arow = row0 + (lane & 15);
    if (arow >= N) arow = N - 1;
    const size_t roff = (size_t)arow * 128 + (lane >> 4) * 8;
    const float* srcs[3] = {a1, a2, xin};
    bf16x8 ahi[3][4], alo[3][4];
    #pragma unroll
    for (int m = 0; m < 3; ++m) {
        const float* rp = srcs[m] + roff;
        #pragma unroll
        for (int t = 0; t < 4; ++t) {
            float4 v0 = *reinterpret_cast<const float4*>(rp + t * 32);
            float4 v1 = *reinterpret_cast<const float4*>(rp + t * 32 + 4);
            float f[8] = {v0.x, v0.y, v0.z, v0.w, v1.x, v1.y, v1.z, v1.w};
            #pragma unroll
            for (int j = 0; j < 8; ++j) {
                short hh, ll;
                split_bf16(f[j], hh, ll);
                ahi[m][t][j] = hh;
                alo[m][t][j] = ll;
            }
        }
    }

    const int colbase = lane & 15;
    const int rbase = row0 + (lane >> 4) * 4;
    #pragma unroll
    for (int c = 0; c < 8; ++c) {
        f32x4 a = {0.f, 0.f, 0.f, 0.f};
        #pragma unroll
        for (int t = 0; t < 4; ++t) {
            #pragma unroll
            for (int m = 0; m < 3; ++m) {
                const short* bp = wp + (size_t)((m * 8 + c) * 4 + t) * 1024 + lane * 16;
                bf16x8 bhi = *reinterpret_cast<const bf16x8*>(bp);
                bf16x8 blo = *reinterpret_cast<const bf16x8*>(bp + 8);
                a = __builtin_amdgcn_mfma_f32_16x16x32_bf16(ahi[m][t], bhi, a, 0, 0, 0);
                a = __builtin_amdgcn_mfma_f32_16x16x32_bf16(ahi[m][t], blo, a, 0, 0, 0);
                a = __builtin_amdgcn_mfma_f32_16x16x32_bf16(alo[m][t], bhi, a, 0, 0, 0);
            }
        }
        int col = c * 16 + colbase;
        float bias = b1[col] + b2[col] + b3[col];
        a[0] += bias; a[1] += bias; a[2] += bias; a[3] += bias;
        #pragma unroll
        for (int r = 0; r < 4; ++r) {
            int rr = rbase + r;
            if (rr < N) h[(size_t)rr * 128 + col] = a[r];
        }
    }
}

// ---------------- relu + row L2 norm ----------------
__global__ __launch_bounds__(256) void relu_rownorm_kernel(float* __restrict__ h, int N)
{
    int row = blockIdx.x * 4 + (threadIdx.x >> 6);
    if (row >= N) return;
    int lane = threadIdx.x & 63;
    float2* p = reinterpret_cast<float2*>(h + (size_t)row * 128) + lane;
    float2 v = *p;
    v.x = fmaxf(v.x, 0.f);
    v.y = fmaxf(v.y, 0.f);
    float ss = v.x * v.x + v.y * v.y;
    #pragma unroll
    for (int m = 1; m < 64; m <<= 1) ss += __shfl_xor(ss, m);
    float sc = 1.f / fmaxf(sqrtf(ss), 1e-12f);
    v.x *= sc; v.y *= sc;
    *p = v;
}

// ---------------- readout (fp32) ----------------
__global__ __launch_bounds__(256) void readout_kernel(
    const float* __restrict__ x, const float* __restrict__ W,
    const float* __restrict__ bias, float* __restrict__ out, int N)
{
    __shared__ float xs[64 * 132];
    const int tid = threadIdx.x;
    const int row0 = blockIdx.x * 64;
    #pragma unroll
    for (int j = 0; j < 8; ++j) {
        int g4 = tid + j * 256;
        int r = g4 >> 5, c4 = g4 & 31;
        float4 v = make_float4(0.f, 0.f, 0.f, 0.f);
        if (row0 + r < N)
            v = reinterpret_cast<const float4*>(x + (size_t)(row0 + r) * D)[c4];
        *reinterpret_cast<float4*>(xs + r * 132 + c4 * 4) = v;
    }
    __syncthreads();

    const int cg = tid & 15;
    const int rg = tid >> 4;
    float a[4][4];
    #pragma unroll
    for (int i = 0; i < 4; ++i)
        #pragma unroll
        for (int j = 0; j < 4; ++j) a[i][j] = 0.f;

    for (int k = 0; k < 128; k += 4) {
        float4 w0 = *reinterpret_cast<const float4*>(W + (size_t)(k + 0) * 64 + cg * 4);
        float4 w1 = *reinterpret_cast<const float4*>(W + (size_t)(k + 1) * 64 + cg * 4);
        float4 w2 = *reinterpret_cast<const float4*>(W + (size_t)(k + 2) * 64 + cg * 4);
        float4 w3 = *reinterpret_cast<const float4*>(W + (size_t)(k + 3) * 64 + cg * 4);
        #pragma unroll
        for (int i = 0; i < 4; ++i) {
            float4 xv = *reinterpret_cast<const float4*>(xs + (rg * 4 + i) * 132 + k);
            a[i][0] += xv.x * w0.x + xv.y * w1.x + xv.z * w2.x + xv.w * w3.x;
            a[i][1] += xv.x * w0.y + xv.y * w1.y + xv.z * w2.y + xv.w * w3.y;
            a[i][2] += xv.x * w0.z + xv.y * w1.z + xv.z * w2.z + xv.w * w3.z;
            a[i][3] += xv.x * w0.w + xv.y * w1.w + xv.z * w2.w + xv.w * w3.w;
        }
    }
    #pragma unroll
    for (int i = 0; i < 4; ++i) {
        int r = row0 + rg * 4 + i;
        if (r < N) {
            float4 o = make_float4(a[i][0] + bias[cg * 4 + 0], a[i][1] + bias[cg * 4 + 1],
                                   a[i][2] + bias[cg * 4 + 2], a[i][3] + bias[cg * 4 + 3]);
            *reinterpret_cast<float4*>(out + (size_t)r * 64 + cg * 4) = o;
        }
    }
}

extern "C" void kernel_launch(void* const* d_in, const int* in_sizes, int n_in,
                              void* d_out, int out_size, void* d_ws, size_t ws_size,
                              hipStream_t stream)
{
    const float* x     = (const float*)d_in[0];
    const int*   ei    = (const int*)d_in[1];
    const float* theta = (const float*)d_in[2];
    const float* Ws2d  = (const float*)d_in[3];
    const float* Wd2s  = (const float*)d_in[4];
    const float* Wself = (const float*)d_in[5];
    const float* bs2d  = (const float*)d_in[6];
    const float* bd2s  = (const float*)d_in[7];
    const float* bself = (const float*)d_in[8];
    const float* W_ro  = (const float*)d_in[9];
    const float* b_ro  = (const float*)d_in[10];
    float* out = (float*)d_out;

    const int N = in_sizes[0] / D;          // 50000
    const int E = in_sizes[2];              // 800000
    const int L = in_sizes[3] / (D * D);    // 2

    const int* src = ei;
    const int* dst = ei + E;

    // Workspace: packed u64[2N] | startv int[N] | s_edge int4[E] | wpack short[L*98304]
    //            | a1 a2 accA accB float[N*D each]
    u64*  packed_out = (u64*)d_ws;                       // N u64
    u64*  packed_in  = packed_out + N;                   // N u64
    int*  startv     = (int*)(packed_in + N);            // N
    int4* s_edge     = (int4*)(startv + N);              // E int4
    short* wpack     = (short*)(s_edge + E);             // L * 98304 shorts
    float* a1   = (float*)(wpack + (size_t)L * 98304);   // N*D
    float* a2   = a1 + (size_t)N * D;                    // N*D
    float* accA = a2 + (size_t)N * D;                    // N*D
    float* accB = accA + (size_t)N * D;                  // N*D

    hipMemsetAsync(packed_out, 0, (size_t)2 * N * sizeof(u64), stream);
    edge_wdeg_kernel<<<(E + 255) / 256, 256, 0, stream>>>(
        theta, src, dst, packed_out, packed_in, E);
    scan_kernel<<<1, 1024, 0, stream>>>(packed_in, startv, N);
    scatter_kernel<<<(E + 255) / 256, 256, 0, stream>>>(
        theta, src, dst, packed_out, packed_in, startv, s_edge, E);
    for (int i = 0; i < L; ++i)
        wpack_kernel<<<(6144 + 255) / 256, 256, 0, stream>>>(
            Ws2d + (size_t)i * D * D, Wd2s + (size_t)i * D * D, Wself + (size_t)i * D * D,
            wpack + (size_t)i * 98304);

    const float* xin = x;
    float* accs[2] = {accA, accB};
    for (int i = 0; i < L; ++i) {
        float* acc = accs[i & 1];
        agg_x_kernel<<<(N + 3) / 4, 256, 0, stream>>>(
            startv, s_edge, xin, a1, a2, N);
        matmul_fused_kernel<<<(N + 63) / 64, 256, 0, stream>>>(
            a1, a2, xin, wpack + (size_t)i * 98304,
            bs2d + (size_t)i * D, bd2s + (size_t)i * D, bself + (size_t)i * D,
            acc, N);
        if (i != L - 1)
            relu_rownorm_kernel<<<(N + 3) / 4, 256, 0, stream>>>(acc, N);
        xin = acc;
    }
    readout_kernel<<<(N + 63) / 64, 256, 0, stream>>>(xin, W_ro, b_ro, out, N);
}

// Round 10
// 498.192 us; speedup vs baseline: 3.7689x; 1.0786x over previous
//
#include <hip/hip_runtime.h>
#include <math.h>

// FuzzyDirGCN — x-space CSR aggregation + fused MFMA matmul (+relu/rownorm
// epilogue) + MFMA readout.  bf16 hi/lo split everywhere (fp32-grade).

constexpr int D = 128;
typedef unsigned long long u64;
typedef __attribute__((ext_vector_type(8))) short bf16x8;
typedef __attribute__((ext_vector_type(4))) float f32x4;

__device__ __forceinline__ u64 pack_wc(float f) {
    return (1ULL << 44) | (u64)(f * 16777216.0f + 0.5f);   // 2^24 fixed point
}
__device__ __forceinline__ void unpack_wc(u64 p, float& sumf, float& cnt) {
    cnt  = (float)(unsigned)(p >> 44);
    sumf = (float)(p & ((1ULL << 44) - 1)) * (1.0f / 16777216.0f);
}

__device__ __forceinline__ void split_bf16(float x, short& hi, short& lo) {
    unsigned xb = __float_as_uint(x);
    hi = (short)(xb >> 16);
    float h = __uint_as_float(xb & 0xffff0000u);
    lo = (short)(__float_as_uint(x - h) >> 16);
}

// ---------------- CSR build ----------------
__global__ __launch_bounds__(256) void edge_wdeg_kernel(
    const float* __restrict__ theta, const int* __restrict__ src, const int* __restrict__ dst,
    u64* __restrict__ packed_out, u64* __restrict__ packed_in, int E)
{
    int e = blockIdx.x * 256 + threadIdx.x;
    if (e >= E) return;
    float c = cosf(theta[e]);
    u64 p = pack_wc(c * c);
    atomicAdd(&packed_out[src[e]], p);
    atomicAdd(&packed_in[dst[e]], p);
}

// Exclusive prefix sum of in-counts; 2 elements per thread per iteration.
__global__ __launch_bounds__(1024) void scan_kernel(
    const u64* __restrict__ packed_in, int* __restrict__ startv, int N)
{
    __shared__ int wsum[16];
    __shared__ int carry;
    if (threadIdx.x == 0) carry = 0;
    __syncthreads();
    const int lane = threadIdx.x & 63, wid = threadIdx.x >> 6;
    for (int base = 0; base < N; base += 2048) {
        int i0 = base + threadIdx.x * 2;
        int i1 = i0 + 1;
        int v0 = (i0 < N) ? (int)(packed_in[i0] >> 44) : 0;
        int v1 = (i1 < N) ? (int)(packed_in[i1] >> 44) : 0;
        int pair = v0 + v1;
        int x = pair;
        #pragma unroll
        for (int d = 1; d < 64; d <<= 1) {
            int t = __shfl_up(x, d);
            if (lane >= d) x += t;
        }
        if (lane == 63) wsum[wid] = x;
        __syncthreads();
        if (wid == 0) {
            int s = (lane < 16) ? wsum[lane] : 0;
            #pragma unroll
            for (int d = 1; d < 16; d <<= 1) {
                int t = __shfl_up(s, d);
                if (lane >= d) s += t;
            }
            if (lane < 16) wsum[lane] = s;
        }
        __syncthreads();
        int woff = (wid == 0) ? 0 : wsum[wid - 1];
        int excl = carry + woff + x - pair;
        if (i0 < N) startv[i0] = excl;
        if (i1 < N) startv[i1] = excl + v0;
        __syncthreads();
        if (threadIdx.x == 1023) carry += wsum[15];
        __syncthreads();
    }
}

__global__ __launch_bounds__(256) void scatter_kernel(
    const float* __restrict__ theta, const int* __restrict__ src, const int* __restrict__ dst,
    const u64* __restrict__ packed_out, const u64* __restrict__ packed_in,
    int* __restrict__ startv, int4* __restrict__ s_edge, int E)
{
    int e = blockIdx.x * 256 + threadIdx.x;
    if (e >= E) return;
    int u = src[e], v = dst[e];
    float s, c;
    sincosf(theta[e], &s, &c);
    float f = c * c, b = s * s;
    float fo, co, fi, ci;
    unpack_wc(packed_out[u], fo, co);
    unpack_wc(packed_in[v], fi, ci);
    float bo = co - fo, bi = ci - fi;            // sin^2 degrees
    f *= rsqrtf(fo * fi + 1e-12f);
    b *= rsqrtf(bo * bi + 1e-12f);
    int pos = atomicAdd(&startv[v], 1);
    s_edge[pos] = make_int4(u, __float_as_int(f), __float_as_int(b), 0);
}

// ---------------- W pre-pack (layer weights, 8 col-frags) ----------------
// wp (ushort): [m:3][c:8][t:4][lane:64][hi/lo:2][j:8]
// element = bf16 of W_m[t*32 + (lane>>4)*8 + j][c*16 + (lane&15)]
__global__ __launch_bounds__(256) void wpack_kernel(
    const float* __restrict__ W1, const float* __restrict__ W2, const float* __restrict__ W3,
    short* __restrict__ wp)
{
    int idx = blockIdx.x * 256 + threadIdx.x;     // ((m*8+c)*4+t)*64 + lane
    if (idx >= 3 * 8 * 4 * 64) return;
    int lane = idx & 63;
    int t = (idx >> 6) & 3;
    int c = (idx >> 8) & 7;
    int m = idx >> 11;
    const float* W = (m == 0) ? W1 : ((m == 1) ? W2 : W3);
    int col  = c * 16 + (lane & 15);
    int row0 = t * 32 + (lane >> 4) * 8;
    short hi[8], lo[8];
    #pragma unroll
    for (int j = 0; j < 8; ++j)
        split_bf16(W[(size_t)(row0 + j) * 128 + col], hi[j], lo[j]);
    short* dst = wp + (size_t)idx * 16;
    #pragma unroll
    for (int j = 0; j < 8; ++j) { dst[j] = hi[j]; dst[8 + j] = lo[j]; }
}

// ---------------- W_ro pre-pack (readout, 4 col-frags of 64 cols) ----------------
// wp_ro: [c:4][t:4][lane:64][hi/lo:2][j:8]; element = W_ro[t*32+(lane>>4)*8+j][c*16+(lane&15)]
__global__ __launch_bounds__(256) void wpack_ro_kernel(
    const float* __restrict__ W, short* __restrict__ wp)
{
    int idx = blockIdx.x * 256 + threadIdx.x;     // (c*4+t)*64 + lane
    if (idx >= 4 * 4 * 64) return;
    int lane = idx & 63;
    int t = (idx >> 6) & 3;
    int c = idx >> 8;
    int col  = c * 16 + (lane & 15);
    int row0 = t * 32 + (lane >> 4) * 8;
    short hi[8], lo[8];
    #pragma unroll
    for (int j = 0; j < 8; ++j)
        split_bf16(W[(size_t)(row0 + j) * 64 + col], hi[j], lo[j]);
    short* dst = wp + (size_t)idx * 16;
    #pragma unroll
    for (int j = 0; j < 8; ++j) { dst[j] = hi[j]; dst[8 + j] = lo[j]; }
}

// ---------------- x-space CSR aggregation (4-deep unroll) ----------------
__global__ __launch_bounds__(256) void agg_x_kernel(
    const int* __restrict__ endv, const int4* __restrict__ s_edge,
    const float* __restrict__ x,
    float* __restrict__ a1, float* __restrict__ a2, int N)
{
    int v = blockIdx.x * 4 + (threadIdx.x >> 6);
    if (v >= N) return;
    int lane = threadIdx.x & 63;
    int beg = (v == 0) ? 0 : endv[v - 1];
    int end = endv[v];
    float2 s1 = make_float2(0.f, 0.f), s2 = make_float2(0.f, 0.f);
    int e = beg;
    for (; e + 3 < end; e += 4) {
        int4 E0 = s_edge[e], E1 = s_edge[e + 1], E2 = s_edge[e + 2], E3 = s_edge[e + 3];
        float2 x0 = reinterpret_cast<const float2*>(x + (size_t)E0.x * 128)[lane];
        float2 x1 = reinterpret_cast<const float2*>(x + (size_t)E1.x * 128)[lane];
        float2 x2 = reinterpret_cast<const float2*>(x + (size_t)E2.x * 128)[lane];
        float2 x3 = reinterpret_cast<const float2*>(x + (size_t)E3.x * 128)[lane];
        float f0 = __int_as_float(E0.y), b0 = __int_as_float(E0.z);
        float f1 = __int_as_float(E1.y), b1 = __int_as_float(E1.z);
        float f2 = __int_as_float(E2.y), b2 = __int_as_float(E2.z);
        float f3 = __int_as_float(E3.y), b3 = __int_as_float(E3.z);
        s1.x = fmaf(f0, x0.x, s1.x); s1.y = fmaf(f0, x0.y, s1.y);
        s2.x = fmaf(b0, x0.x, s2.x); s2.y = fmaf(b0, x0.y, s2.y);
        s1.x = fmaf(f1, x1.x, s1.x); s1.y = fmaf(f1, x1.y, s1.y);
        s2.x = fmaf(b1, x1.x, s2.x); s2.y = fmaf(b1, x1.y, s2.y);
        s1.x = fmaf(f2, x2.x, s1.x); s1.y = fmaf(f2, x2.y, s1.y);
        s2.x = fmaf(b2, x2.x, s2.x); s2.y = fmaf(b2, x2.y, s2.y);
        s1.x = fmaf(f3, x3.x, s1.x); s1.y = fmaf(f3, x3.y, s1.y);
        s2.x = fmaf(b3, x3.x, s2.x); s2.y = fmaf(b3, x3.y, s2.y);
    }
    for (; e < end; ++e) {
        int4 E0 = s_edge[e];
        float f0 = __int_as_float(E0.y), b0 = __int_as_float(E0.z);
        float2 x0 = reinterpret_cast<const float2*>(x + (size_t)E0.x * 128)[lane];
        s1.x = fmaf(f0, x0.x, s1.x); s1.y = fmaf(f0, x0.y, s1.y);
        s2.x = fmaf(b0, x0.x, s2.x); s2.y = fmaf(b0, x0.y, s2.y);
    }
    reinterpret_cast<float2*>(a1 + (size_t)v * 128)[lane] = s1;
    reinterpret_cast<float2*>(a2 + (size_t)v * 128)[lane] = s2;
}

// ---------------- fused 3-stream MFMA matmul + optional relu/rownorm ----------------
// h = a1@W1 + a2@W2 + x@W3 + (b1+b2+b3); if NORM: h = relu(h)/max(||row||,eps).
// Block: 4 waves, 64 rows; wave: 16 rows x 128 cols.  144 MFMA/wave.
template <bool NORM>
__global__ __launch_bounds__(256, 2) void matmul_fused_kernel(
    const float* __restrict__ a1, const float* __restrict__ a2,
    const float* __restrict__ xin, const short* __restrict__ wp,
    const float* __restrict__ b1, const float* __restrict__ b2, const float* __restrict__ b3,
    float* __restrict__ h, int N)
{
    const int lane = threadIdx.x & 63, wid = threadIdx.x >> 6;
    const int row0 = blockIdx.x * 64 + wid * 16;

    int arow = row0 + (lane & 15);
    if (arow >= N) arow = N - 1;
    const size_t roff = (size_t)arow * 128 + (lane >> 4) * 8;
    const float* srcs[3] = {a1, a2, xin};
    bf16x8 ahi[3][4], alo[3][4];
    #pragma unroll
    for (int m = 0; m < 3; ++m) {
        const float* rp = srcs[m] + roff;
        #pragma unroll
        for (int t = 0; t < 4; ++t) {
            float4 v0 = *reinterpret_cast<const float4*>(rp + t * 32);
            float4 v1 = *reinterpret_cast<const float4*>(rp + t * 32 + 4);
            float f[8] = {v0.x, v0.y, v0.z, v0.w, v1.x, v1.y, v1.z, v1.w};
            #pragma unroll
            for (int j = 0; j < 8; ++j) {
                short hh, ll;
                split_bf16(f[j], hh, ll);
                ahi[m][t][j] = hh;
                alo[m][t][j] = ll;
            }
        }
    }

    const int colbase = lane & 15;
    const int rbase = row0 + (lane >> 4) * 4;
    f32x4 acc[8];
    #pragma unroll
    for (int c = 0; c < 8; ++c) {
        f32x4 a = {0.f, 0.f, 0.f, 0.f};
        #pragma unroll
        for (int t = 0; t < 4; ++t) {
            #pragma unroll
            for (int m = 0; m < 3; ++m) {
                const short* bp = wp + (size_t)((m * 8 + c) * 4 + t) * 1024 + lane * 16;
                bf16x8 bhi = *reinterpret_cast<const bf16x8*>(bp);
                bf16x8 blo = *reinterpret_cast<const bf16x8*>(bp + 8);
                a = __builtin_amdgcn_mfma_f32_16x16x32_bf16(ahi[m][t], bhi, a, 0, 0, 0);
                a = __builtin_amdgcn_mfma_f32_16x16x32_bf16(ahi[m][t], blo, a, 0, 0, 0);
                a = __builtin_amdgcn_mfma_f32_16x16x32_bf16(alo[m][t], bhi, a, 0, 0, 0);
            }
        }
        int col = c * 16 + colbase;
        float bias = b1[col] + b2[col] + b3[col];
        a[0] += bias; a[1] += bias; a[2] += bias; a[3] += bias;
        acc[c] = a;
    }

    if (NORM) {
        // relu, then row L2 norm: cols of row (rbase+r) live in this lane's 8
        // frags and the other 15 lanes of its 16-lane group.
        #pragma unroll
        for (int c = 0; c < 8; ++c) {
            acc[c][0] = fmaxf(acc[c][0], 0.f);
            acc[c][1] = fmaxf(acc[c][1], 0.f);
            acc[c][2] = fmaxf(acc[c][2], 0.f);
            acc[c][3] = fmaxf(acc[c][3], 0.f);
        }
        float ss[4] = {0.f, 0.f, 0.f, 0.f};
        #pragma unroll
        for (int c = 0; c < 8; ++c) {
            ss[0] = fmaf(acc[c][0], acc[c][0], ss[0]);
            ss[1] = fmaf(acc[c][1], acc[c][1], ss[1]);
            ss[2] = fmaf(acc[c][2], acc[c][2], ss[2]);
            ss[3] = fmaf(acc[c][3], acc[c][3], ss[3]);
        }
        #pragma unroll
        for (int r = 0; r < 4; ++r) {
            #pragma unroll
            for (int m = 1; m < 16; m <<= 1) ss[r] += __shfl_xor(ss[r], m);
        }
        float sc[4];
        #pragma unroll
        for (int r = 0; r < 4; ++r) sc[r] = 1.f / fmaxf(sqrtf(ss[r]), 1e-12f);
        #pragma unroll
        for (int c = 0; c < 8; ++c) {
            acc[c][0] *= sc[0]; acc[c][1] *= sc[1];
            acc[c][2] *= sc[2]; acc[c][3] *= sc[3];
        }
    }

    #pragma unroll
    for (int c = 0; c < 8; ++c) {
        int col = c * 16 + colbase;
        #pragma unroll
        for (int r = 0; r < 4; ++r) {
            int rr = rbase + r;
            if (rr < N) h[(size_t)rr * 128 + col] = acc[c][r];
        }
    }
}

// ---------------- MFMA readout: out = x@W_ro + b_ro ----------------
__global__ __launch_bounds__(256, 2) void readout_mfma_kernel(
    const float* __restrict__ xin, const short* __restrict__ wp,
    const float* __restrict__ bias, float* __restrict__ out, int N)
{
    const int lane = threadIdx.x & 63, wid = threadIdx.x >> 6;
    const int row0 = blockIdx.x * 64 + wid * 16;

    int arow = row0 + (lane & 15);
    if (arow >= N) arow = N - 1;
    const float* rp = xin + (size_t)arow * 128 + (lane >> 4) * 8;
    bf16x8 ahi[4], alo[4];
    #pragma unroll
    for (int t = 0; t < 4; ++t) {
        float4 v0 = *reinterpret_cast<const float4*>(rp + t * 32);
        float4 v1 = *reinterpret_cast<const float4*>(rp + t * 32 + 4);
        float f[8] = {v0.x, v0.y, v0.z, v0.w, v1.x, v1.y, v1.z, v1.w};
        #pragma unroll
        for (int j = 0; j < 8; ++j) {
            short hh, ll;
            split_bf16(f[j], hh, ll);
            ahi[t][j] = hh;
            alo[t][j] = ll;
        }
    }

    const int colbase = lane & 15;
    const int rbase = row0 + (lane >> 4) * 4;
    #pragma unroll
    for (int c = 0; c < 4; ++c) {
        f32x4 a = {0.f, 0.f, 0.f, 0.f};
        #pragma unroll
        for (int t = 0; t < 4; ++t) {
            const short* bp = wp + (size_t)((c * 4 + t) * 64 + lane) * 16;
            bf16x8 bhi = *reinterpret_cast<const bf16x8*>(bp);
            bf16x8 blo = *reinterpret_cast<const bf16x8*>(bp + 8);
            a = __builtin_amdgcn_mfma_f32_16x16x32_bf16(ahi[t], bhi, a, 0, 0, 0);
            a = __builtin_amdgcn_mfma_f32_16x16x32_bf16(ahi[t], blo, a, 0, 0, 0);
            a = __builtin_amdgcn_mfma_f32_16x16x32_bf16(alo[t], bhi, a, 0, 0, 0);
        }
        int col = c * 16 + colbase;
        float bv = bias[col];
        a[0] += bv; a[1] += bv; a[2] += bv; a[3] += bv;
        #pragma unroll
        for (int r = 0; r < 4; ++r) {
            int rr = rbase + r;
            if (rr < N) out[(size_t)rr * 64 + col] = a[r];
        }
    }
}

extern "C" void kernel_launch(void* const* d_in, const int* in_sizes, int n_in,
                              void* d_out, int out_size, void* d_ws, size_t ws_size,
                              hipStream_t stream)
{
    const float* x     = (const float*)d_in[0];
    const int*   ei    = (const int*)d_in[1];
    const float* theta = (const float*)d_in[2];
    const float* Ws2d  = (const float*)d_in[3];
    const float* Wd2s  = (const float*)d_in[4];
    const float* Wself = (const float*)d_in[5];
    const float* bs2d  = (const float*)d_in[6];
    const float* bd2s  = (const float*)d_in[7];
    const float* bself = (const float*)d_in[8];
    const float* W_ro  = (const float*)d_in[9];
    const float* b_ro  = (const float*)d_in[10];
    float* out = (float*)d_out;

    const int N = in_sizes[0] / D;          // 50000
    const int E = in_sizes[2];              // 800000
    const int L = in_sizes[3] / (D * D);    // 2

    const int* src = ei;
    const int* dst = ei + E;

    // Workspace: packed u64[2N] | startv int[N] | s_edge int4[E]
    //            | wpack short[L*98304] | wpack_ro short[16384]
    //            | a1 a2 accA accB float[N*D each]
    u64*  packed_out = (u64*)d_ws;                        // N u64
    u64*  packed_in  = packed_out + N;                    // N u64
    int*  startv     = (int*)(packed_in + N);             // N
    int4* s_edge     = (int4*)(startv + N);               // E int4
    short* wpack     = (short*)(s_edge + E);              // L * 98304 shorts
    short* wpack_ro  = wpack + (size_t)L * 98304;         // 16384 shorts
    float* a1   = (float*)(wpack_ro + 16384);             // N*D
    float* a2   = a1 + (size_t)N * D;                     // N*D
    float* accA = a2 + (size_t)N * D;                     // N*D
    float* accB = accA + (size_t)N * D;                   // N*D

    hipMemsetAsync(packed_out, 0, (size_t)2 * N * sizeof(u64), stream);
    edge_wdeg_kernel<<<(E + 255) / 256, 256, 0, stream>>>(
        theta, src, dst, packed_out, packed_in, E);
    scan_kernel<<<1, 1024, 0, stream>>>(packed_in, startv, N);
    scatter_kernel<<<(E + 255) / 256, 256, 0, stream>>>(
        theta, src, dst, packed_out, packed_in, startv, s_edge, E);
    for (int i = 0; i < L; ++i)
        wpack_kernel<<<(6144 + 255) / 256, 256, 0, stream>>>(
            Ws2d + (size_t)i * D * D, Wd2s + (size_t)i * D * D, Wself + (size_t)i * D * D,
            wpack + (size_t)i * 98304);
    wpack_ro_kernel<<<4, 256, 0, stream>>>(W_ro, wpack_ro);

    const float* xin = x;
    float* accs[2] = {accA, accB};
    for (int i = 0; i < L; ++i) {
        float* acc = accs[i & 1];
        agg_x_kernel<<<(N + 3) / 4, 256, 0, stream>>>(
            startv, s_edge, xin, a1, a2, N);
        if (i != L - 1)
            matmul_fused_kernel<true><<<(N + 63) / 64, 256, 0, stream>>>(
                a1, a2, xin, wpack + (size_t)i * 98304,
                bs2d + (size_t)i * D, bd2s + (size_t)i * D, bself + (size_t)i * D,
                acc, N);
        else
            matmul_fused_kernel<false><<<(N + 63) / 64, 256, 0, stream>>>(
                a1, a2, xin, wpack + (size_t)i * 98304,
                bs2d + (size_t)i * D, bd2s + (size_t)i * D, bself + (size_t)i * D,
                acc, N);
        xin = acc;
    }
    readout_mfma_kernel<<<(N + 63) / 64, 256, 0, stream>>>(xin, wpack_ro, b_ro, out, N);
}

// Round 11
// 483.659 us; speedup vs baseline: 3.8821x; 1.0300x over previous
//
#include <hip/hip_runtime.h>
#include <math.h>

// FuzzyDirGCN — x-space CSR aggregation + fused MFMA matmul (+relu/rownorm or
// fused readout epilogue).  bf16 hi/lo split (fp32-grade accuracy).
// Norm is separable: w = c^2 * rsqrt(deg_out[u]) * rsqrt(deg_in[v]); src-side
// factor folded at scatter, dst-side factor applied once per node in agg_x.

constexpr int D = 128;
typedef unsigned long long u64;
typedef __attribute__((ext_vector_type(8))) short bf16x8;
typedef __attribute__((ext_vector_type(4))) float f32x4;

__device__ __forceinline__ u64 pack_wc(float f) {
    return (1ULL << 44) | (u64)(f * 16777216.0f + 0.5f);   // 2^24 fixed point
}
__device__ __forceinline__ void unpack_wc(u64 p, float& sumf, float& cnt) {
    cnt  = (float)(unsigned)(p >> 44);
    sumf = (float)(p & ((1ULL << 44) - 1)) * (1.0f / 16777216.0f);
}

__device__ __forceinline__ void split_bf16(float x, short& hi, short& lo) {
    unsigned xb = __float_as_uint(x);
    hi = (short)(xb >> 16);
    float h = __uint_as_float(xb & 0xffff0000u);
    lo = (short)(__float_as_uint(x - h) >> 16);
}

// ---------------- CSR build ----------------
__global__ __launch_bounds__(256) void edge_wdeg_kernel(
    const float* __restrict__ theta, const int* __restrict__ src, const int* __restrict__ dst,
    u64* __restrict__ packed_out, u64* __restrict__ packed_in, int E)
{
    int e = blockIdx.x * 256 + threadIdx.x;
    if (e >= E) return;
    float c = cosf(theta[e]);
    u64 p = pack_wc(c * c);
    atomicAdd(&packed_out[src[e]], p);
    atomicAdd(&packed_in[dst[e]], p);
}

// Exclusive prefix sum of in-counts; 2 elements per thread per iteration.
__global__ __launch_bounds__(1024) void scan_kernel(
    const u64* __restrict__ packed_in, int* __restrict__ startv, int N)
{
    __shared__ int wsum[16];
    __shared__ int carry;
    if (threadIdx.x == 0) carry = 0;
    __syncthreads();
    const int lane = threadIdx.x & 63, wid = threadIdx.x >> 6;
    for (int base = 0; base < N; base += 2048) {
        int i0 = base + threadIdx.x * 2;
        int i1 = i0 + 1;
        int v0 = (i0 < N) ? (int)(packed_in[i0] >> 44) : 0;
        int v1 = (i1 < N) ? (int)(packed_in[i1] >> 44) : 0;
        int pair = v0 + v1;
        int x = pair;
        #pragma unroll
        for (int d = 1; d < 64; d <<= 1) {
            int t = __shfl_up(x, d);
            if (lane >= d) x += t;
        }
        if (lane == 63) wsum[wid] = x;
        __syncthreads();
        if (wid == 0) {
            int s = (lane < 16) ? wsum[lane] : 0;
            #pragma unroll
            for (int d = 1; d < 16; d <<= 1) {
                int t = __shfl_up(s, d);
                if (lane >= d) s += t;
            }
            if (lane < 16) wsum[lane] = s;
        }
        __syncthreads();
        int woff = (wid == 0) ? 0 : wsum[wid - 1];
        int excl = carry + woff + x - pair;
        if (i0 < N) startv[i0] = excl;
        if (i1 < N) startv[i1] = excl + v0;
        __syncthreads();
        if (threadIdx.x == 1023) carry += wsum[15];
        __syncthreads();
    }
}

// Scatter: s_edge[pos] = {src, c^2*rsqrt(deg_out_f[u]), s^2*rsqrt(deg_out_b[u]), 0}
__global__ __launch_bounds__(256) void scatter_kernel(
    const float* __restrict__ theta, const int* __restrict__ src, const int* __restrict__ dst,
    const u64* __restrict__ packed_out,
    int* __restrict__ startv, int4* __restrict__ s_edge, int E)
{
    int e = blockIdx.x * 256 + threadIdx.x;
    if (e >= E) return;
    int u = src[e], v = dst[e];
    float s, c;
    sincosf(theta[e], &s, &c);
    float fo, co;
    unpack_wc(packed_out[u], fo, co);
    float bo = co - fo;                       // sin^2 out-degree
    float f = c * c * (fo > 0.f ? rsqrtf(fo) : 0.f);
    float b = s * s * (bo > 0.f ? rsqrtf(bo) : 0.f);
    int pos = atomicAdd(&startv[v], 1);
    s_edge[pos] = make_int4(u, __float_as_int(f), __float_as_int(b), 0);
}

// ---------------- W pre-pack (all layers + readout, one launch) ----------------
// layer entry r = ((m*8+c)*4+t)*64+lane : bf16 hi/lo of W_m[t*32+(lane>>4)*8+j][c*16+(lane&15)]
// ro entry    r = ((c*4)+t)*64+lane     : same for W_ro (64 cols -> c in 0..3)
__global__ __launch_bounds__(256) void wpack_all_kernel(
    const float* __restrict__ Ws2d, const float* __restrict__ Wd2s,
    const float* __restrict__ Wself, const float* __restrict__ W_ro,
    short* __restrict__ wp, short* __restrict__ wp_ro, int L)
{
    int idx = blockIdx.x * 256 + threadIdx.x;
    int layerTotal = L * 6144;
    if (idx < layerTotal) {
        int layer = idx / 6144;
        int r = idx - layer * 6144;           // ((m*8+c)*4+t)*64 + lane
        int lane = r & 63;
        int t = (r >> 6) & 3;
        int c = (r >> 8) & 7;
        int m = r >> 11;
        const float* W = ((m == 0) ? Ws2d : ((m == 1) ? Wd2s : Wself)) + (size_t)layer * D * D;
        int col  = c * 16 + (lane & 15);
        int row0 = t * 32 + (lane >> 4) * 8;
        short* dst = wp + (size_t)layer * 98304 + (size_t)r * 16;
        #pragma unroll
        for (int j = 0; j < 8; ++j) {
            short hi, lo;
            split_bf16(W[(size_t)(row0 + j) * 128 + col], hi, lo);
            dst[j] = hi; dst[8 + j] = lo;
        }
    } else if (idx < layerTotal + 1024) {
        int r = idx - layerTotal;             // (c*4+t)*64 + lane
        int lane = r & 63;
        int t = (r >> 6) & 3;
        int c = r >> 8;
        int col  = c * 16 + (lane & 15);
        int row0 = t * 32 + (lane >> 4) * 8;
        short* dst = wp_ro + (size_t)r * 16;
        #pragma unroll
        for (int j = 0; j < 8; ++j) {
            short hi, lo;
            split_bf16(W_ro[(size_t)(row0 + j) * 64 + col], hi, lo);
            dst[j] = hi; dst[8 + j] = lo;
        }
    }
}

// ---------------- x-space CSR aggregation (4-deep unroll, v-side norm) ----------------
__global__ __launch_bounds__(256) void agg_x_kernel(
    const int* __restrict__ endv, const int4* __restrict__ s_edge,
    const u64* __restrict__ packed_in, const float* __restrict__ x,
    float* __restrict__ a1, float* __restrict__ a2, int N)
{
    int v = blockIdx.x * 4 + (threadIdx.x >> 6);
    if (v >= N) return;
    int lane = threadIdx.x & 63;
    int beg = (v == 0) ? 0 : endv[v - 1];
    int end = endv[v];
    float2 s1 = make_float2(0.f, 0.f), s2 = make_float2(0.f, 0.f);
    int e = beg;
    for (; e + 3 < end; e += 4) {
        int4 E0 = s_edge[e], E1 = s_edge[e + 1], E2 = s_edge[e + 2], E3 = s_edge[e + 3];
        float2 x0 = reinterpret_cast<const float2*>(x + (size_t)E0.x * 128)[lane];
        float2 x1 = reinterpret_cast<const float2*>(x + (size_t)E1.x * 128)[lane];
        float2 x2 = reinterpret_cast<const float2*>(x + (size_t)E2.x * 128)[lane];
        float2 x3 = reinterpret_cast<const float2*>(x + (size_t)E3.x * 128)[lane];
        float f0 = __int_as_float(E0.y), b0 = __int_as_float(E0.z);
        float f1 = __int_as_float(E1.y), b1 = __int_as_float(E1.z);
        float f2 = __int_as_float(E2.y), b2 = __int_as_float(E2.z);
        float f3 = __int_as_float(E3.y), b3 = __int_as_float(E3.z);
        s1.x = fmaf(f0, x0.x, s1.x); s1.y = fmaf(f0, x0.y, s1.y);
        s2.x = fmaf(b0, x0.x, s2.x); s2.y = fmaf(b0, x0.y, s2.y);
        s1.x = fmaf(f1, x1.x, s1.x); s1.y = fmaf(f1, x1.y, s1.y);
        s2.x = fmaf(b1, x1.x, s2.x); s2.y = fmaf(b1, x1.y, s2.y);
        s1.x = fmaf(f2, x2.x, s1.x); s1.y = fmaf(f2, x2.y, s1.y);
        s2.x = fmaf(b2, x2.x, s2.x); s2.y = fmaf(b2, x2.y, s2.y);
        s1.x = fmaf(f3, x3.x, s1.x); s1.y = fmaf(f3, x3.y, s1.y);
        s2.x = fmaf(b3, x3.x, s2.x); s2.y = fmaf(b3, x3.y, s2.y);
    }
    for (; e < end; ++e) {
        int4 E0 = s_edge[e];
        float f0 = __int_as_float(E0.y), b0 = __int_as_float(E0.z);
        float2 x0 = reinterpret_cast<const float2*>(x + (size_t)E0.x * 128)[lane];
        s1.x = fmaf(f0, x0.x, s1.x); s1.y = fmaf(f0, x0.y, s1.y);
        s2.x = fmaf(b0, x0.x, s2.x); s2.y = fmaf(b0, x0.y, s2.y);
    }
    // v-side factors: rsqrt(deg_in_f[v]), rsqrt(deg_in_b[v])  (guard 0-degree)
    float fi, ci;
    unpack_wc(packed_in[v], fi, ci);
    float bi = ci - fi;
    float pif = fi > 0.f ? rsqrtf(fi) : 0.f;
    float pib = bi > 0.f ? rsqrtf(bi) : 0.f;
    s1.x *= pif; s1.y *= pif;
    s2.x *= pib; s2.y *= pib;
    reinterpret_cast<float2*>(a1 + (size_t)v * 128)[lane] = s1;
    reinterpret_cast<float2*>(a2 + (size_t)v * 128)[lane] = s2;
}

// ---------------- fused 3-stream MFMA matmul ----------------
// h = a1@W1 + a2@W2 + x@W3 + (b1+b2+b3)
// NORM: h = relu(h)/max(||row||,eps), store h.
// RO:   out = h@W_ro + b_ro (LDS transpose + 48 MFMA), h NOT stored.
template <bool NORM, bool RO>
__global__ __launch_bounds__(256, 2) void matmul_fused_kernel(
    const float* __restrict__ a1, const float* __restrict__ a2,
    const float* __restrict__ xin, const short* __restrict__ wp,
    const float* __restrict__ b1, const float* __restrict__ b2, const float* __restrict__ b3,
    const short* __restrict__ wp_ro, const float* __restrict__ b_ro,
    float* __restrict__ h, float* __restrict__ out, int N)
{
    __shared__ float ls[4][16 * 132];
    const int lane = threadIdx.x & 63, wid = threadIdx.x >> 6;
    const int row0 = blockIdx.x * 64 + wid * 16;

    int arow = row0 + (lane & 15);
    if (arow >= N) arow = N - 1;
    const size_t roff = (size_t)arow * 128 + (lane >> 4) * 8;
    const float* srcs[3] = {a1, a2, xin};
    bf16x8 ahi[3][4], alo[3][4];
    #pragma unroll
    for (int m = 0; m < 3; ++m) {
        const float* rp = srcs[m] + roff;
        #pragma unroll
        for (int t = 0; t < 4; ++t) {
            float4 v0 = *reinterpret_cast<const float4*>(rp + t * 32);
            float4 v1 = *reinterpret_cast<const float4*>(rp + t * 32 + 4);
            float f[8] = {v0.x, v0.y, v0.z, v0.w, v1.x, v1.y, v1.z, v1.w};
            #pragma unroll
            for (int j = 0; j < 8; ++j) {
                short hh, ll;
                split_bf16(f[j], hh, ll);
                ahi[m][t][j] = hh;
                alo[m][t][j] = ll;
            }
        }
    }

    const int colbase = lane & 15;
    const int rbase = row0 + (lane >> 4) * 4;
    f32x4 acc[8];
    #pragma unroll
    for (int c = 0; c < 8; ++c) {
        f32x4 a = {0.f, 0.f, 0.f, 0.f};
        #pragma unroll
        for (int t = 0; t < 4; ++t) {
            #pragma unroll
            for (int m = 0; m < 3; ++m) {
                const short* bp = wp + (size_t)((m * 8 + c) * 4 + t) * 1024 + lane * 16;
                bf16x8 bhi = *reinterpret_cast<const bf16x8*>(bp);
                bf16x8 blo = *reinterpret_cast<const bf16x8*>(bp + 8);
                a = __builtin_amdgcn_mfma_f32_16x16x32_bf16(ahi[m][t], bhi, a, 0, 0, 0);
                a = __builtin_amdgcn_mfma_f32_16x16x32_bf16(ahi[m][t], blo, a, 0, 0, 0);
                a = __builtin_amdgcn_mfma_f32_16x16x32_bf16(alo[m][t], bhi, a, 0, 0, 0);
            }
        }
        int col = c * 16 + colbase;
        float bias = b1[col] + b2[col] + b3[col];
        a[0] += bias; a[1] += bias; a[2] += bias; a[3] += bias;
        acc[c] = a;
    }

    if (NORM) {
        #pragma unroll
        for (int c = 0; c < 8; ++c) {
            acc[c][0] = fmaxf(acc[c][0], 0.f);
            acc[c][1] = fmaxf(acc[c][1], 0.f);
            acc[c][2] = fmaxf(acc[c][2], 0.f);
            acc[c][3] = fmaxf(acc[c][3], 0.f);
        }
        float ss[4] = {0.f, 0.f, 0.f, 0.f};
        #pragma unroll
        for (int c = 0; c < 8; ++c) {
            ss[0] = fmaf(acc[c][0], acc[c][0], ss[0]);
            ss[1] = fmaf(acc[c][1], acc[c][1], ss[1]);
            ss[2] = fmaf(acc[c][2], acc[c][2], ss[2]);
            ss[3] = fmaf(acc[c][3], acc[c][3], ss[3]);
        }
        #pragma unroll
        for (int r = 0; r < 4; ++r) {
            #pragma unroll
            for (int m = 1; m < 16; m <<= 1) ss[r] += __shfl_xor(ss[r], m);
        }
        float sc[4];
        #pragma unroll
        for (int r = 0; r < 4; ++r) sc[r] = 1.f / fmaxf(sqrtf(ss[r]), 1e-12f);
        #pragma unroll
        for (int c = 0; c < 8; ++c) {
            acc[c][0] *= sc[0]; acc[c][1] *= sc[1];
            acc[c][2] *= sc[2]; acc[c][3] *= sc[3];
        }
    }

    if (!RO) {
        #pragma unroll
        for (int c = 0; c < 8; ++c) {
            int col = c * 16 + colbase;
            #pragma unroll
            for (int r = 0; r < 4; ++r) {
                int rr = rbase + r;
                if (rr < N) h[(size_t)rr * 128 + col] = acc[c][r];
            }
        }
    } else {
        // out = h@W_ro + b_ro: transpose h via padded LDS, rebuild A-frags.
        #pragma unroll
        for (int c = 0; c < 8; ++c) {
            int col = c * 16 + colbase;
            #pragma unroll
            for (int r = 0; r < 4; ++r)
                ls[wid][((lane >> 4) * 4 + r) * 132 + col] = acc[c][r];
        }
        __syncthreads();
        const float* lrow = &ls[wid][(lane & 15) * 132 + (lane >> 4) * 8];
        bf16x8 hhi[4], hlo[4];
        #pragma unroll
        for (int t = 0; t < 4; ++t) {
            float4 v0 = *reinterpret_cast<const float4*>(lrow + t * 32);
            float4 v1 = *reinterpret_cast<const float4*>(lrow + t * 32 + 4);
            float f[8] = {v0.x, v0.y, v0.z, v0.w, v1.x, v1.y, v1.z, v1.w};
            #pragma unroll
            for (int j = 0; j < 8; ++j) {
                short hh, ll;
                split_bf16(f[j], hh, ll);
                hhi[t][j] = hh;
                hlo[t][j] = ll;
            }
        }
        #pragma unroll
        for (int c2 = 0; c2 < 4; ++c2) {
            f32x4 a = {0.f, 0.f, 0.f, 0.f};
            #pragma unroll
            for (int t = 0; t < 4; ++t) {
                const short* bp = wp_ro + (size_t)((c2 * 4 + t) * 64 + lane) * 16;
                bf16x8 bhi = *reinterpret_cast<const bf16x8*>(bp);
                bf16x8 blo = *reinterpret_cast<const bf16x8*>(bp + 8);
                a = __builtin_amdgcn_mfma_f32_16x16x32_bf16(hhi[t], bhi, a, 0, 0, 0);
                a = __builtin_amdgcn_mfma_f32_16x16x32_bf16(hhi[t], blo, a, 0, 0, 0);
                a = __builtin_amdgcn_mfma_f32_16x16x32_bf16(hlo[t], bhi, a, 0, 0, 0);
            }
            int col = c2 * 16 + colbase;
            float bv = b_ro[col];
            a[0] += bv; a[1] += bv; a[2] += bv; a[3] += bv;
            #pragma unroll
            for (int r = 0; r < 4; ++r) {
                int rr = rbase + r;
                if (rr < N) out[(size_t)rr * 64 + col] = a[r];
            }
        }
    }
}

extern "C" void kernel_launch(void* const* d_in, const int* in_sizes, int n_in,
                              void* d_out, int out_size, void* d_ws, size_t ws_size,
                              hipStream_t stream)
{
    const float* x     = (const float*)d_in[0];
    const int*   ei    = (const int*)d_in[1];
    const float* theta = (const float*)d_in[2];
    const float* Ws2d  = (const float*)d_in[3];
    const float* Wd2s  = (const float*)d_in[4];
    const float* Wself = (const float*)d_in[5];
    const float* bs2d  = (const float*)d_in[6];
    const float* bd2s  = (const float*)d_in[7];
    const float* bself = (const float*)d_in[8];
    const float* W_ro  = (const float*)d_in[9];
    const float* b_ro  = (const float*)d_in[10];
    float* out = (float*)d_out;

    const int N = in_sizes[0] / D;          // 50000
    const int E = in_sizes[2];              // 800000
    const int L = in_sizes[3] / (D * D);    // 2

    const int* src = ei;
    const int* dst = ei + E;

    // Workspace: packed u64[2N] | startv int[N] | s_edge int4[E]
    //            | wpack short[L*98304] | wpack_ro short[16384]
    //            | a1 a2 accA accB float[N*D each]
    u64*  packed_out = (u64*)d_ws;                        // N u64
    u64*  packed_in  = packed_out + N;                    // N u64
    int*  startv     = (int*)(packed_in + N);             // N
    int4* s_edge     = (int4*)(startv + N);               // E int4
    short* wpack     = (short*)(s_edge + E);              // L * 98304 shorts
    short* wpack_ro  = wpack + (size_t)L * 98304;         // 16384 shorts
    float* a1   = (float*)(wpack_ro + 16384);             // N*D
    float* a2   = a1 + (size_t)N * D;                     // N*D
    float* accA = a2 + (size_t)N * D;                     // N*D
    float* accB = accA + (size_t)N * D;                   // N*D

    hipMemsetAsync(packed_out, 0, (size_t)2 * N * sizeof(u64), stream);
    edge_wdeg_kernel<<<(E + 255) / 256, 256, 0, stream>>>(
        theta, src, dst, packed_out, packed_in, E);
    scan_kernel<<<1, 1024, 0, stream>>>(packed_in, startv, N);
    scatter_kernel<<<(E + 255) / 256, 256, 0, stream>>>(
        theta, src, dst, packed_out, startv, s_edge, E);
    wpack_all_kernel<<<(L * 6144 + 1024 + 255) / 256, 256, 0, stream>>>(
        Ws2d, Wd2s, Wself, W_ro, wpack, wpack_ro, L);

    const float* xin = x;
    float* accs[2] = {accA, accB};
    for (int i = 0; i < L; ++i) {
        float* acc = accs[i & 1];
        agg_x_kernel<<<(N + 3) / 4, 256, 0, stream>>>(
            startv, s_edge, packed_in, xin, a1, a2, N);
        if (i != L - 1)
            matmul_fused_kernel<true, false><<<(N + 63) / 64, 256, 0, stream>>>(
                a1, a2, xin, wpack + (size_t)i * 98304,
                bs2d + (size_t)i * D, bd2s + (size_t)i * D, bself + (size_t)i * D,
                wpack_ro, b_ro, acc, out, N);
        else
            matmul_fused_kernel<false, true><<<(N + 63) / 64, 256, 0, stream>>>(
                a1, a2, xin, wpack + (size_t)i * 98304,
                bs2d + (size_t)i * D, bd2s + (size_t)i * D, bself + (size_t)i * D,
                wpack_ro, b_ro, acc, out, N);
        xin = acc;
    }
}

// Round 13
// 463.824 us; speedup vs baseline: 4.0482x; 1.0428x over previous
//
#include <hip/hip_runtime.h>
#include <math.h>

// FuzzyDirGCN — x-space CSR aggregation + fused MFMA matmul (+relu/rownorm or
// fused readout epilogue).  bf16 hi/lo split (fp32-grade accuracy).
// CSR build is atomic-minimal: the histogram atomic's RETURN VALUE gives each
// edge its within-bin rank, so the scatter pass needs no atomics at all.

constexpr int D = 128;
typedef unsigned long long u64;
typedef __attribute__((ext_vector_type(8))) short bf16x8;
typedef __attribute__((ext_vector_type(4))) float f32x4;

__device__ __forceinline__ u64 pack_wc(float f) {
    return (1ULL << 44) | (u64)(f * 16777216.0f + 0.5f);   // 2^24 fixed point
}
__device__ __forceinline__ void unpack_wc(u64 p, float& sumf, float& cnt) {
    cnt  = (float)(unsigned)(p >> 44);
    sumf = (float)(p & ((1ULL << 44) - 1)) * (1.0f / 16777216.0f);
}

__device__ __forceinline__ void split_bf16(float x, short& hi, short& lo) {
    unsigned xb = __float_as_uint(x);
    hi = (short)(xb >> 16);
    float h = __uint_as_float(xb & 0xffff0000u);
    lo = (short)(__float_as_uint(x - h) >> 16);
}

// ---------------- CSR build pass 1: degrees + within-bin rank ----------------
__global__ __launch_bounds__(256) void edge_wdeg_kernel(
    const float* __restrict__ theta, const int* __restrict__ src, const int* __restrict__ dst,
    u64* __restrict__ packed_out, u64* __restrict__ packed_in,
    int* __restrict__ rank, int E)
{
    int e = blockIdx.x * 256 + threadIdx.x;
    if (e >= E) return;
    float c = cosf(theta[e]);
    u64 p = pack_wc(c * c);
    atomicAdd(&packed_out[src[e]], p);
    u64 old = atomicAdd(&packed_in[dst[e]], p);
    rank[e] = (int)(old >> 44);               // edges before this one in bin dst[e]
}

// Exclusive prefix sum of in-counts; 2 elements per thread per iteration.
__global__ __launch_bounds__(1024) void scan_kernel(
    const u64* __restrict__ packed_in, int* __restrict__ startv, int N)
{
    __shared__ int wsum[16];
    __shared__ int carry;
    if (threadIdx.x == 0) carry = 0;
    __syncthreads();
    const int lane = threadIdx.x & 63, wid = threadIdx.x >> 6;
    for (int base = 0; base < N; base += 2048) {
        int i0 = base + threadIdx.x * 2;
        int i1 = i0 + 1;
        int v0 = (i0 < N) ? (int)(packed_in[i0] >> 44) : 0;
        int v1 = (i1 < N) ? (int)(packed_in[i1] >> 44) : 0;
        int pair = v0 + v1;
        int x = pair;
        #pragma unroll
        for (int d = 1; d < 64; d <<= 1) {
            int t = __shfl_up(x, d);
            if (lane >= d) x += t;
        }
        if (lane == 63) wsum[wid] = x;
        __syncthreads();
        if (wid == 0) {
            int s = (lane < 16) ? wsum[lane] : 0;
            #pragma unroll
            for (int d = 1; d < 16; d <<= 1) {
                int t = __shfl_up(s, d);
                if (lane >= d) s += t;
            }
            if (lane < 16) wsum[lane] = s;
        }
        __syncthreads();
        int woff = (wid == 0) ? 0 : wsum[wid - 1];
        int excl = carry + woff + x - pair;
        if (i0 < N) startv[i0] = excl;
        if (i1 < N) startv[i1] = excl + v0;
        __syncthreads();
        if (threadIdx.x == 1023) carry += wsum[15];
        __syncthreads();
    }
}

// Scatter (no atomics): pos = startv[dst] + rank[e].
// s_edge[pos] = {src, c^2*rsqrt(deg_out_f[u]), s^2*rsqrt(deg_out_b[u]), 0}
__global__ __launch_bounds__(256) void scatter_kernel(
    const float* __restrict__ theta, const int* __restrict__ src, const int* __restrict__ dst,
    const u64* __restrict__ packed_out, const int* __restrict__ startv,
    const int* __restrict__ rank, int4* __restrict__ s_edge, int E)
{
    int e = blockIdx.x * 256 + threadIdx.x;
    if (e >= E) return;
    int u = src[e], v = dst[e];
    float s, c;
    sincosf(theta[e], &s, &c);
    float fo, co;
    unpack_wc(packed_out[u], fo, co);
    float bo = co - fo;                       // sin^2 out-degree
    float f = c * c * (fo > 0.f ? rsqrtf(fo) : 0.f);
    float b = s * s * (bo > 0.f ? rsqrtf(bo) : 0.f);
    int pos = startv[v] + rank[e];
    s_edge[pos] = make_int4(u, __float_as_int(f), __float_as_int(b), 0);
}

// ---------------- W pre-pack (all layers + readout, one launch) ----------------
// layer entry r = ((m*8+c)*4+t)*64+lane : bf16 hi/lo of W_m[t*32+(lane>>4)*8+j][c*16+(lane&15)]
// ro entry    r = ((c*4)+t)*64+lane     : same for W_ro (64 cols -> c in 0..3)
__global__ __launch_bounds__(256) void wpack_all_kernel(
    const float* __restrict__ Ws2d, const float* __restrict__ Wd2s,
    const float* __restrict__ Wself, const float* __restrict__ W_ro,
    short* __restrict__ wp, short* __restrict__ wp_ro, int L)
{
    int idx = blockIdx.x * 256 + threadIdx.x;
    int layerTotal = L * 6144;
    if (idx < layerTotal) {
        int layer = idx / 6144;
        int r = idx - layer * 6144;           // ((m*8+c)*4+t)*64 + lane
        int lane = r & 63;
        int t = (r >> 6) & 3;
        int c = (r >> 8) & 7;
        int m = r >> 11;
        const float* W = ((m == 0) ? Ws2d : ((m == 1) ? Wd2s : Wself)) + (size_t)layer * D * D;
        int col  = c * 16 + (lane & 15);
        int row0 = t * 32 + (lane >> 4) * 8;
        short* dst = wp + (size_t)layer * 98304 + (size_t)r * 16;
        #pragma unroll
        for (int j = 0; j < 8; ++j) {
            short hi, lo;
            split_bf16(W[(size_t)(row0 + j) * 128 + col], hi, lo);
            dst[j] = hi; dst[8 + j] = lo;
        }
    } else if (idx < layerTotal + 1024) {
        int r = idx - layerTotal;             // (c*4+t)*64 + lane
        int lane = r & 63;
        int t = (r >> 6) & 3;
        int c = r >> 8;
        int col  = c * 16 + (lane & 15);
        int row0 = t * 32 + (lane >> 4) * 8;
        short* dst = wp_ro + (size_t)r * 16;
        #pragma unroll
        for (int j = 0; j < 8; ++j) {
            short hi, lo;
            split_bf16(W_ro[(size_t)(row0 + j) * 64 + col], hi, lo);
            dst[j] = hi; dst[8 + j] = lo;
        }
    }
}

// ---------------- x-space CSR aggregation (4-deep unroll, v-side norm) ----------------
// Bin v spans startv[v] .. (v+1<N ? startv[v+1] : E).
__global__ __launch_bounds__(256) void agg_x_kernel(
    const int* __restrict__ startv, const int4* __restrict__ s_edge,
    const u64* __restrict__ packed_in, const float* __restrict__ x,
    float* __restrict__ a1, float* __restrict__ a2, int N, int E)
{
    int v = blockIdx.x * 4 + (threadIdx.x >> 6);
    if (v >= N) return;
    int lane = threadIdx.x & 63;
    int beg = startv[v];
    int end = (v + 1 < N) ? startv[v + 1] : E;
    float2 s1 = make_float2(0.f, 0.f), s2 = make_float2(0.f, 0.f);
    int e = beg;
    for (; e + 3 < end; e += 4) {
        int4 E0 = s_edge[e], E1 = s_edge[e + 1], E2 = s_edge[e + 2], E3 = s_edge[e + 3];
        float2 x0 = reinterpret_cast<const float2*>(x + (size_t)E0.x * 128)[lane];
        float2 x1 = reinterpret_cast<const float2*>(x + (size_t)E1.x * 128)[lane];
        float2 x2 = reinterpret_cast<const float2*>(x + (size_t)E2.x * 128)[lane];
        float2 x3 = reinterpret_cast<const float2*>(x + (size_t)E3.x * 128)[lane];
        float f0 = __int_as_float(E0.y), b0 = __int_as_float(E0.z);
        float f1 = __int_as_float(E1.y), b1 = __int_as_float(E1.z);
        float f2 = __int_as_float(E2.y), b2 = __int_as_float(E2.z);
        float f3 = __int_as_float(E3.y), b3 = __int_as_float(E3.z);
        s1.x = fmaf(f0, x0.x, s1.x); s1.y = fmaf(f0, x0.y, s1.y);
        s2.x = fmaf(b0, x0.x, s2.x); s2.y = fmaf(b0, x0.y, s2.y);
        s1.x = fmaf(f1, x1.x, s1.x); s1.y = fmaf(f1, x1.y, s1.y);
        s2.x = fmaf(b1, x1.x, s2.x); s2.y = fmaf(b1, x1.y, s2.y);
        s1.x = fmaf(f2, x2.x, s1.x); s1.y = fmaf(f2, x2.y, s1.y);
        s2.x = fmaf(b2, x2.x, s2.x); s2.y = fmaf(b2, x2.y, s2.y);
        s1.x = fmaf(f3, x3.x, s1.x); s1.y = fmaf(f3, x3.y, s1.y);
        s2.x = fmaf(b3, x3.x, s2.x); s2.y = fmaf(b3, x3.y, s2.y);
    }
    for (; e < end; ++e) {
        int4 E0 = s_edge[e];
        float f0 = __int_as_float(E0.y), b0 = __int_as_float(E0.z);
        float2 x0 = reinterpret_cast<const float2*>(x + (size_t)E0.x * 128)[lane];
        s1.x = fmaf(f0, x0.x, s1.x); s1.y = fmaf(f0, x0.y, s1.y);
        s2.x = fmaf(b0, x0.x, s2.x); s2.y = fmaf(b0, x0.y, s2.y);
    }
    // v-side factors: rsqrt(deg_in_f[v]), rsqrt(deg_in_b[v])  (guard 0-degree)
    float fi, ci;
    unpack_wc(packed_in[v], fi, ci);
    float bi = ci - fi;
    float pif = fi > 0.f ? rsqrtf(fi) : 0.f;
    float pib = bi > 0.f ? rsqrtf(bi) : 0.f;
    s1.x *= pif; s1.y *= pif;
    s2.x *= pib; s2.y *= pib;
    reinterpret_cast<float2*>(a1 + (size_t)v * 128)[lane] = s1;
    reinterpret_cast<float2*>(a2 + (size_t)v * 128)[lane] = s2;
}

// ---------------- fused 3-stream MFMA matmul ----------------
// h = a1@W1 + a2@W2 + x@W3 + (b1+b2+b3)
// NORM: h = relu(h)/max(||row||,eps), store h.
// RO:   out = h@W_ro + b_ro (LDS transpose + 48 MFMA), h NOT stored.
template <bool NORM, bool RO>
__global__ __launch_bounds__(256, 2) void matmul_fused_kernel(
    const float* __restrict__ a1, const float* __restrict__ a2,
    const float* __restrict__ xin, const short* __restrict__ wp,
    const float* __restrict__ b1, const float* __restrict__ b2, const float* __restrict__ b3,
    const short* __restrict__ wp_ro, const float* __restrict__ b_ro,
    float* __restrict__ h, float* __restrict__ out, int N)
{
    __shared__ float ls[4][16 * 132];
    const int lane = threadIdx.x & 63, wid = threadIdx.x >> 6;
    const int row0 = blockIdx.x * 64 + wid * 16;

    int arow = row0 + (lane & 15);
    if (arow >= N) arow = N - 1;
    const size_t roff = (size_t)arow * 128 + (lane >> 4) * 8;
    const float* srcs[3] = {a1, a2, xin};
    bf16x8 ahi[3][4], alo[3][4];
    #pragma unroll
    for (int m = 0; m < 3; ++m) {
        const float* rp = srcs[m] + roff;
        #pragma unroll
        for (int t = 0; t < 4; ++t) {
            float4 v0 = *reinterpret_cast<const float4*>(rp + t * 32);
            float4 v1 = *reinterpret_cast<const float4*>(rp + t * 32 + 4);
            float f[8] = {v0.x, v0.y, v0.z, v0.w, v1.x, v1.y, v1.z, v1.w};
            #pragma unroll
            for (int j = 0; j < 8; ++j) {
                short hh, ll;
                split_bf16(f[j], hh, ll);
                ahi[m][t][j] = hh;
                alo[m][t][j] = ll;
            }
        }
    }

    const int colbase = lane & 15;
    const int rbase = row0 + (lane >> 4) * 4;
    f32x4 acc[8];
    #pragma unroll
    for (int c = 0; c < 8; ++c) {
        f32x4 a = {0.f, 0.f, 0.f, 0.f};
        #pragma unroll
        for (int t = 0; t < 4; ++t) {
            #pragma unroll
            for (int m = 0; m < 3; ++m) {
                const short* bp = wp + (size_t)((m * 8 + c) * 4 + t) * 1024 + lane * 16;
                bf16x8 bhi = *reinterpret_cast<const bf16x8*>(bp);
                bf16x8 blo = *reinterpret_cast<const bf16x8*>(bp + 8);
                a = __builtin_amdgcn_mfma_f32_16x16x32_bf16(ahi[m][t], bhi, a, 0, 0, 0);
                a = __builtin_amdgcn_mfma_f32_16x16x32_bf16(ahi[m][t], blo, a, 0, 0, 0);
                a = __builtin_amdgcn_mfma_f32_16x16x32_bf16(alo[m][t], bhi, a, 0, 0, 0);
            }
        }
        int col = c * 16 + colbase;
        float bias = b1[col] + b2[col] + b3[col];
        a[0] += bias; a[1] += bias; a[2] += bias; a[3] += bias;
        acc[c] = a;
    }

    if (NORM) {
        #pragma unroll
        for (int c = 0; c < 8; ++c) {
            acc[c][0] = fmaxf(acc[c][0], 0.f);
            acc[c][1] = fmaxf(acc[c][1], 0.f);
            acc[c][2] = fmaxf(acc[c][2], 0.f);
            acc[c][3] = fmaxf(acc[c][3], 0.f);
        }
        float ss[4] = {0.f, 0.f, 0.f, 0.f};
        #pragma unroll
        for (int c = 0; c < 8; ++c) {
            ss[0] = fmaf(acc[c][0], acc[c][0], ss[0]);
            ss[1] = fmaf(acc[c][1], acc[c][1], ss[1]);
            ss[2] = fmaf(acc[c][2], acc[c][2], ss[2]);
            ss[3] = fmaf(acc[c][3], acc[c][3], ss[3]);
        }
        #pragma unroll
        for (int r = 0; r < 4; ++r) {
            #pragma unroll
            for (int m = 1; m < 16; m <<= 1) ss[r] += __shfl_xor(ss[r], m);
        }
        float sc[4];
        #pragma unroll
        for (int r = 0; r < 4; ++r) sc[r] = 1.f / fmaxf(sqrtf(ss[r]), 1e-12f);
        #pragma unroll
        for (int c = 0; c < 8; ++c) {
            acc[c][0] *= sc[0]; acc[c][1] *= sc[1];
            acc[c][2] *= sc[2]; acc[c][3] *= sc[3];
        }
    }

    if (!RO) {
        #pragma unroll
        for (int c = 0; c < 8; ++c) {
            int col = c * 16 + colbase;
            #pragma unroll
            for (int r = 0; r < 4; ++r) {
                int rr = rbase + r;
                if (rr < N) h[(size_t)rr * 128 + col] = acc[c][r];
            }
        }
    } else {
        // out = h@W_ro + b_ro: transpose h via padded LDS, rebuild A-frags.
        #pragma unroll
        for (int c = 0; c < 8; ++c) {
            int col = c * 16 + colbase;
            #pragma unroll
            for (int r = 0; r < 4; ++r)
                ls[wid][((lane >> 4) * 4 + r) * 132 + col] = acc[c][r];
        }
        __syncthreads();
        const float* lrow = &ls[wid][(lane & 15) * 132 + (lane >> 4) * 8];
        bf16x8 hhi[4], hlo[4];
        #pragma unroll
        for (int t = 0; t < 4; ++t) {
            float4 v0 = *reinterpret_cast<const float4*>(lrow + t * 32);
            float4 v1 = *reinterpret_cast<const float4*>(lrow + t * 32 + 4);
            float f[8] = {v0.x, v0.y, v0.z, v0.w, v1.x, v1.y, v1.z, v1.w};
            #pragma unroll
            for (int j = 0; j < 8; ++j) {
                short hh, ll;
                split_bf16(f[j], hh, ll);
                hhi[t][j] = hh;
                hlo[t][j] = ll;
            }
        }
        #pragma unroll
        for (int c2 = 0; c2 < 4; ++c2) {
            f32x4 a = {0.f, 0.f, 0.f, 0.f};
            #pragma unroll
            for (int t = 0; t < 4; ++t) {
                const short* bp = wp_ro + (size_t)((c2 * 4 + t) * 64 + lane) * 16;
                bf16x8 bhi = *reinterpret_cast<const bf16x8*>(bp);
                bf16x8 blo = *reinterpret_cast<const bf16x8*>(bp + 8);
                a = __builtin_amdgcn_mfma_f32_16x16x32_bf16(hhi[t], bhi, a, 0, 0, 0);
                a = __builtin_amdgcn_mfma_f32_16x16x32_bf16(hhi[t], blo, a, 0, 0, 0);
                a = __builtin_amdgcn_mfma_f32_16x16x32_bf16(hlo[t], bhi, a, 0, 0, 0);
            }
            int col = c2 * 16 + colbase;
            float bv = b_ro[col];
            a[0] += bv; a[1] += bv; a[2] += bv; a[3] += bv;
            #pragma unroll
            for (int r = 0; r < 4; ++r) {
                int rr = rbase + r;
                if (rr < N) out[(size_t)rr * 64 + col] = a[r];
            }
        }
    }
}

extern "C" void kernel_launch(void* const* d_in, const int* in_sizes, int n_in,
                              void* d_out, int out_size, void* d_ws, size_t ws_size,
                              hipStream_t stream)
{
    const float* x     = (const float*)d_in[0];
    const int*   ei    = (const int*)d_in[1];
    const float* theta = (const float*)d_in[2];
    const float* Ws2d  = (const float*)d_in[3];
    const float* Wd2s  = (const float*)d_in[4];
    const float* Wself = (const float*)d_in[5];
    const float* bs2d  = (const float*)d_in[6];
    const float* bd2s  = (const float*)d_in[7];
    const float* bself = (const float*)d_in[8];
    const float* W_ro  = (const float*)d_in[9];
    const float* b_ro  = (const float*)d_in[10];
    float* out = (float*)d_out;

    const int N = in_sizes[0] / D;          // 50000
    const int E = in_sizes[2];              // 800000
    const int L = in_sizes[3] / (D * D);    // 2

    const int* src = ei;
    const int* dst = ei + E;

    // Workspace: packed u64[2N] | startv int[N] | rank int[E] | s_edge int4[E]
    //            | wpack short[L*98304] | wpack_ro short[16384]
    //            | a1 a2 accA accB float[N*D each]
    u64*  packed_out = (u64*)d_ws;                        // N u64
    u64*  packed_in  = packed_out + N;                    // N u64
    int*  startv     = (int*)(packed_in + N);             // N
    int*  rank       = startv + N;                        // E
    int4* s_edge     = (int4*)(rank + E);                 // E int4
    short* wpack     = (short*)(s_edge + E);              // L * 98304 shorts
    short* wpack_ro  = wpack + (size_t)L * 98304;         // 16384 shorts
    float* a1   = (float*)(wpack_ro + 16384);             // N*D
    float* a2   = a1 + (size_t)N * D;                     // N*D
    float* accA = a2 + (size_t)N * D;                     // N*D
    float* accB = accA + (size_t)N * D;                   // N*D

    hipMemsetAsync(packed_out, 0, (size_t)2 * N * sizeof(u64), stream);
    edge_wdeg_kernel<<<(E + 255) / 256, 256, 0, stream>>>(
        theta, src, dst, packed_out, packed_in, rank, E);
    scan_kernel<<<1, 1024, 0, stream>>>(packed_in, startv, N);
    scatter_kernel<<<(E + 255) / 256, 256, 0, stream>>>(
        theta, src, dst, packed_out, startv, rank, s_edge, E);
    wpack_all_kernel<<<(L * 6144 + 1024 + 255) / 256, 256, 0, stream>>>(
        Ws2d, Wd2s, Wself, W_ro, wpack, wpack_ro, L);

    const float* xin = x;
    float* accs[2] = {accA, accB};
    for (int i = 0; i < L; ++i) {
        float* acc = accs[i & 1];
        agg_x_kernel<<<(N + 3) / 4, 256, 0, stream>>>(
            startv, s_edge, packed_in, xin, a1, a2, N, E);
        if (i != L - 1)
            matmul_fused_kernel<true, false><<<(N + 63) / 64, 256, 0, stream>>>(
                a1, a2, xin, wpack + (size_t)i * 98304,
                bs2d + (size_t)i * D, bd2s + (size_t)i * D, bself + (size_t)i * D,
                wpack_ro, b_ro, acc, out, N);
        else
            matmul_fused_kernel<false, true><<<(N + 63) / 64, 256, 0, stream>>>(
                a1, a2, xin, wpack + (size_t)i * 98304,
                bs2d + (size_t)i * D, bd2s + (size_t)i * D, bself + (size_t)i * D,
                wpack_ro, b_ro, acc, out, N);
        xin = acc;
    }
}